// Round 1
// baseline (17809.184 us; speedup 1.0000x reference)
//
#include <hip/hip_runtime.h>
#include <cstdint>
#include <cstddef>

#define N_NODES 89250
#define F0 500
#define F1 512
#define F2 256
#define F3 7

#define BM 128
#define BN 128
#define BKK 16

static inline int cdiv_i(int a, int b) { return (a + b - 1) / b; }

// ---------------- degree count + inverse ----------------
__global__ void count_kernel(const int* __restrict__ dst, float* __restrict__ cnt, int E) {
  int stride = gridDim.x * blockDim.x;
  for (int i = blockIdx.x * blockDim.x + threadIdx.x; i < E; i += stride)
    atomicAdd(&cnt[dst[i]], 1.0f);
}

__global__ void invert_kernel(float* __restrict__ cnt, int n) {
  int i = blockIdx.x * blockDim.x + threadIdx.x;
  if (i < n) cnt[i] = 1.0f / fmaxf(cnt[i], 1.0f);
}

// ---------------- scatter-add aggregation (atomic) ----------------
// C4 = channels/4. Thread handles one (edge, float4-chunk).
template<int C4>
__global__ void scatter_kernel(const float* __restrict__ x, const int* __restrict__ src,
                               const int* __restrict__ dst, float* __restrict__ agg, int E) {
  const long long total = (long long)E * C4;
  const long long stride = (long long)gridDim.x * blockDim.x;
  for (long long idx = (long long)blockIdx.x * blockDim.x + threadIdx.x; idx < total; idx += stride) {
    const int e  = (int)(idx / C4);
    const int c4 = (int)(idx - (long long)e * C4);
    const float4 v = *reinterpret_cast<const float4*>(x + (size_t)src[e] * (C4 * 4) + c4 * 4);
    float* p = agg + (size_t)dst[e] * (C4 * 4) + c4 * 4;
    atomicAdd(p + 0, v.x);
    atomicAdd(p + 1, v.y);
    atomicAdd(p + 2, v.z);
    atomicAdd(p + 3, v.w);
  }
}

// ---------------- fused dual GEMM: C = (scale[n]*A1[n,:])@B1.T + A2@B2.T + bias (+relu) ----------------
// A1,A2: [Nrows,K] row-major. B1,B2: [J,K] row-major (i.e. we compute A@B.T). J % 128 == 0.
__global__ __launch_bounds__(256) void gemm_dual(
    const float* __restrict__ A1, const float* __restrict__ scale,
    const float* __restrict__ A2,
    const float* __restrict__ B1, const float* __restrict__ B2,
    const float* __restrict__ bias, float* __restrict__ Cout,
    int Nrows, int K, int J, int relu)
{
  __shared__ float As[BKK][BM + 4];   // row stride 132 floats = 528B (16B aligned)
  __shared__ float Bs[BKK][BN + 4];
  const int tid = threadIdx.x;
  const int bm = blockIdx.x * BM;
  const int bn = blockIdx.y * BN;
  const int tr = tid >> 4;   // 0..15 -> rows tr*8 .. tr*8+7
  const int tc = tid & 15;   // cols tc*4..tc*4+3 and 64+tc*4..
  const int lk = tid & 3;    // float4 slot in K (lk*4)
  const int lm = tid >> 2;   // 0..63

  float acc[8][8];
#pragma unroll
  for (int i = 0; i < 8; ++i)
#pragma unroll
    for (int j = 0; j < 8; ++j) acc[i][j] = 0.0f;

  for (int s = 0; s < 2; ++s) {
    const float* __restrict__ A = s ? A2 : A1;
    const float* __restrict__ B = s ? B2 : B1;
    for (int k0 = 0; k0 < K; k0 += BKK) {
      __syncthreads();   // protect previous iteration's LDS reads
      const int kk = k0 + lk * 4;
      // A tile
#pragma unroll
      for (int h = 0; h < 2; ++h) {
        const int row = bm + lm + h * 64;
        float4 v = make_float4(0.f, 0.f, 0.f, 0.f);
        if (row < Nrows && kk + 4 <= K)
          v = *reinterpret_cast<const float4*>(A + (size_t)row * K + kk);
        if (s == 0) {
          const float sc = (row < Nrows) ? scale[row] : 0.0f;
          v.x *= sc; v.y *= sc; v.z *= sc; v.w *= sc;
        }
        As[lk * 4 + 0][lm + h * 64] = v.x;
        As[lk * 4 + 1][lm + h * 64] = v.y;
        As[lk * 4 + 2][lm + h * 64] = v.z;
        As[lk * 4 + 3][lm + h * 64] = v.w;
      }
      // B tile
#pragma unroll
      for (int h = 0; h < 2; ++h) {
        const int row = bn + lm + h * 64;
        float4 v = make_float4(0.f, 0.f, 0.f, 0.f);
        if (row < J && kk + 4 <= K)
          v = *reinterpret_cast<const float4*>(B + (size_t)row * K + kk);
        Bs[lk * 4 + 0][lm + h * 64] = v.x;
        Bs[lk * 4 + 1][lm + h * 64] = v.y;
        Bs[lk * 4 + 2][lm + h * 64] = v.z;
        Bs[lk * 4 + 3][lm + h * 64] = v.w;
      }
      __syncthreads();
#pragma unroll
      for (int k = 0; k < BKK; ++k) {
        float a[8], b[8];
#pragma unroll
        for (int i = 0; i < 8; ++i) a[i] = As[k][tr * 8 + i];
#pragma unroll
        for (int j = 0; j < 4; ++j) {
          b[j]     = Bs[k][tc * 4 + j];
          b[4 + j] = Bs[k][64 + tc * 4 + j];
        }
#pragma unroll
        for (int i = 0; i < 8; ++i)
#pragma unroll
          for (int j = 0; j < 8; ++j)
            acc[i][j] = fmaf(a[i], b[j], acc[i][j]);
      }
    }
  }

  // epilogue: bias + relu + float4 stores (cols split tc*4 and 64+tc*4)
  const int c0 = bn + tc * 4;
  const int c1 = bn + 64 + tc * 4;
  const float4 bb0 = *reinterpret_cast<const float4*>(bias + c0);
  const float4 bb1 = *reinterpret_cast<const float4*>(bias + c1);
#pragma unroll
  for (int i = 0; i < 8; ++i) {
    const int row = bm + tr * 8 + i;
    if (row >= Nrows) continue;
    float4 v0, v1;
    v0.x = acc[i][0] + bb0.x; v0.y = acc[i][1] + bb0.y;
    v0.z = acc[i][2] + bb0.z; v0.w = acc[i][3] + bb0.w;
    v1.x = acc[i][4] + bb1.x; v1.y = acc[i][5] + bb1.y;
    v1.z = acc[i][6] + bb1.z; v1.w = acc[i][7] + bb1.w;
    if (relu) {
      v0.x = fmaxf(v0.x, 0.f); v0.y = fmaxf(v0.y, 0.f);
      v0.z = fmaxf(v0.z, 0.f); v0.w = fmaxf(v0.w, 0.f);
      v1.x = fmaxf(v1.x, 0.f); v1.y = fmaxf(v1.y, 0.f);
      v1.z = fmaxf(v1.z, 0.f); v1.w = fmaxf(v1.w, 0.f);
    }
    *reinterpret_cast<float4*>(Cout + (size_t)row * J + c0) = v0;
    *reinterpret_cast<float4*>(Cout + (size_t)row * J + c1) = v1;
  }
}

// ---------------- layer 3 (J=7): one wave per node ----------------
__global__ __launch_bounds__(256) void layer3_kernel(
    const float* __restrict__ agg, const float* __restrict__ scale,
    const float* __restrict__ h2,
    const float* __restrict__ wl, const float* __restrict__ wr,
    const float* __restrict__ bias, float* __restrict__ out, int N)
{
  const int gtid = blockIdx.x * blockDim.x + threadIdx.x;
  const int node = gtid >> 6;
  const int lane = threadIdx.x & 63;
  if (node >= N) return;
  const float4 a4 = *reinterpret_cast<const float4*>(agg + (size_t)node * F2 + lane * 4);
  const float4 x4 = *reinterpret_cast<const float4*>(h2 + (size_t)node * F2 + lane * 4);
  const float sc = scale[node];
#pragma unroll
  for (int j = 0; j < F3; ++j) {
    const float4 l4 = *reinterpret_cast<const float4*>(wl + j * F2 + lane * 4);
    const float4 r4 = *reinterpret_cast<const float4*>(wr + j * F2 + lane * 4);
    float t = sc * (a4.x * l4.x + a4.y * l4.y + a4.z * l4.z + a4.w * l4.w)
            + (x4.x * r4.x + x4.y * r4.y + x4.z * r4.z + x4.w * r4.w);
#pragma unroll
    for (int m = 1; m < 64; m <<= 1) t += __shfl_xor(t, m, 64);
    if (lane == 0) out[(size_t)node * F3 + j] = t + bias[j];
  }
}

extern "C" void kernel_launch(void* const* d_in, const int* in_sizes, int n_in,
                              void* d_out, int out_size, void* d_ws, size_t ws_size,
                              hipStream_t stream) {
  const float* x    = (const float*)d_in[0];
  const int*   ei   = (const int*)d_in[1];
  const float* w_l1 = (const float*)d_in[2];
  const float* w_r1 = (const float*)d_in[3];
  const float* b1   = (const float*)d_in[4];
  const float* w_l2 = (const float*)d_in[5];
  const float* w_r2 = (const float*)d_in[6];
  const float* b2   = (const float*)d_in[7];
  const float* w_l3 = (const float*)d_in[8];
  const float* w_r3 = (const float*)d_in[9];
  const float* b3   = (const float*)d_in[10];
  float* out = (float*)d_out;

  const int E = in_sizes[1] / 2;
  const int* src = ei;
  const int* dst = ei + E;

  // workspace layout (floats): inv_cnt[N] | agg[N*512] (reused x3) | h1[N*512] | h2[N*256]
  float* ws      = (float*)d_ws;
  float* inv_cnt = ws;
  float* agg     = inv_cnt + N_NODES;
  float* h1      = agg + (size_t)N_NODES * 512;
  float* h2      = h1 + (size_t)N_NODES * 512;

  // degree counts -> inverse
  hipMemsetAsync(inv_cnt, 0, N_NODES * sizeof(float), stream);
  count_kernel<<<cdiv_i(E, 256), 256, 0, stream>>>(dst, inv_cnt, E);
  invert_kernel<<<cdiv_i(N_NODES, 256), 256, 0, stream>>>(inv_cnt, N_NODES);

  // ---- layer 1: agg = scatter(x), h1 = relu(mean@wl1.T + x@wr1.T + b1)
  hipMemsetAsync(agg, 0, (size_t)N_NODES * F0 * sizeof(float), stream);
  scatter_kernel<F0 / 4><<<4096, 256, 0, stream>>>(x, src, dst, agg, E);
  {
    dim3 g(cdiv_i(N_NODES, BM), F1 / BN);
    gemm_dual<<<g, 256, 0, stream>>>(agg, inv_cnt, x, w_l1, w_r1, b1, h1, N_NODES, F0, F1, 1);
  }

  // ---- layer 2
  hipMemsetAsync(agg, 0, (size_t)N_NODES * F1 * sizeof(float), stream);
  scatter_kernel<F1 / 4><<<4096, 256, 0, stream>>>(h1, src, dst, agg, E);
  {
    dim3 g(cdiv_i(N_NODES, BM), F2 / BN);
    gemm_dual<<<g, 256, 0, stream>>>(agg, inv_cnt, h1, w_l2, w_r2, b2, h2, N_NODES, F1, F2, 1);
  }

  // ---- layer 3 (tiny J=7)
  hipMemsetAsync(agg, 0, (size_t)N_NODES * F2 * sizeof(float), stream);
  scatter_kernel<F2 / 4><<<4096, 256, 0, stream>>>(h2, src, dst, agg, E);
  layer3_kernel<<<cdiv_i(N_NODES, 4), 256, 0, stream>>>(agg, inv_cnt, h2, w_l3, w_r3, b3, out, N_NODES);
}

// Round 2
// 3001.524 us; speedup vs baseline: 5.9334x; 5.9334x over previous
//
#include <hip/hip_runtime.h>
#include <cstdint>
#include <cstddef>

#define N_NODES 89250
#define F0 500
#define F1 512
#define F2 256
#define F3 7

#define BM 128
#define BN 128
#define BKK 16

static inline int cdiv_i(int a, int b) { return (a + b - 1) / b; }

// ---------------- CSR build ----------------
__global__ void degree_kernel(const int* __restrict__ dst, int* __restrict__ cnt, int E) {
  int stride = gridDim.x * blockDim.x;
  for (int i = blockIdx.x * blockDim.x + threadIdx.x; i < E; i += stride)
    atomicAdd(&cnt[dst[i]], 1);
}

// single-block exclusive scan over n elements (n ~ 89K, 1024 threads)
__global__ __launch_bounds__(1024) void scan_kernel(const int* __restrict__ cnt,
                                                    int* __restrict__ row_ptr, int n) {
  __shared__ int sm[1024];
  __shared__ int carry_s;
  if (threadIdx.x == 0) carry_s = 0;
  __syncthreads();
  for (int base = 0; base < n; base += 1024) {
    const int i = base + threadIdx.x;
    const int v = (i < n) ? cnt[i] : 0;
    sm[threadIdx.x] = v;
    __syncthreads();
    for (int off = 1; off < 1024; off <<= 1) {
      int t = (threadIdx.x >= off) ? sm[threadIdx.x - off] : 0;
      __syncthreads();
      sm[threadIdx.x] += t;
      __syncthreads();
    }
    if (i < n) row_ptr[i] = carry_s + sm[threadIdx.x] - v;
    __syncthreads();
    if (threadIdx.x == 0) carry_s += sm[1023];
    __syncthreads();
  }
  if (threadIdx.x == 0) row_ptr[n] = carry_s;
}

__global__ void cursor_init_kernel(const int* __restrict__ row_ptr, int* __restrict__ cursor, int n) {
  int i = blockIdx.x * blockDim.x + threadIdx.x;
  if (i < n) cursor[i] = row_ptr[i];
}

__global__ void fill_kernel(const int* __restrict__ src, const int* __restrict__ dst,
                            int* __restrict__ cursor, int* __restrict__ csr_src, int E) {
  int stride = gridDim.x * blockDim.x;
  for (int i = blockIdx.x * blockDim.x + threadIdx.x; i < E; i += stride) {
    const int p = atomicAdd(&cursor[dst[i]], 1);
    csr_src[p] = src[i];
  }
}

// ---------------- gather-mean aggregation ----------------
// C channels, TPN threads per node (TPN >= C/4), 256-thread blocks.
template<int C, int TPN>
__global__ __launch_bounds__(256) void gather_mean(
    const float* __restrict__ x, const int* __restrict__ row_ptr,
    const int* __restrict__ csr_src, float* __restrict__ agg, int N)
{
  constexpr int C4 = C / 4;
  constexpr int NPB = 256 / TPN;
  const int node = blockIdx.x * NPB + threadIdx.x / TPN;
  const int t = threadIdx.x % TPN;
  if (node >= N) return;
  const int beg = row_ptr[node];
  const int end = row_ptr[node + 1];
  if (t >= C4) return;
  float4 acc = make_float4(0.f, 0.f, 0.f, 0.f);
  int j = beg;
  for (; j + 1 < end; j += 2) {
    const int s0 = csr_src[j];
    const int s1 = csr_src[j + 1];
    const float4 v0 = *reinterpret_cast<const float4*>(x + (size_t)s0 * C + t * 4);
    const float4 v1 = *reinterpret_cast<const float4*>(x + (size_t)s1 * C + t * 4);
    acc.x += v0.x + v1.x; acc.y += v0.y + v1.y;
    acc.z += v0.z + v1.z; acc.w += v0.w + v1.w;
  }
  if (j < end) {
    const int s0 = csr_src[j];
    const float4 v0 = *reinterpret_cast<const float4*>(x + (size_t)s0 * C + t * 4);
    acc.x += v0.x; acc.y += v0.y; acc.z += v0.z; acc.w += v0.w;
  }
  const float inv = 1.0f / (float)max(end - beg, 1);
  acc.x *= inv; acc.y *= inv; acc.z *= inv; acc.w *= inv;
  *reinterpret_cast<float4*>(agg + (size_t)node * C + t * 4) = acc;
}

// ---------------- fused dual GEMM: C = A1@B1.T + A2@B2.T + bias (+relu) ----------------
__global__ __launch_bounds__(256) void gemm_dual(
    const float* __restrict__ A1, const float* __restrict__ A2,
    const float* __restrict__ B1, const float* __restrict__ B2,
    const float* __restrict__ bias, float* __restrict__ Cout,
    int Nrows, int K, int J, int relu)
{
  __shared__ float As[BKK][BM + 4];
  __shared__ float Bs[BKK][BN + 4];
  const int tid = threadIdx.x;
  const int bm = blockIdx.x * BM;
  const int bn = blockIdx.y * BN;
  const int tr = tid >> 4;
  const int tc = tid & 15;
  const int lk = tid & 3;
  const int lm = tid >> 2;

  float acc[8][8];
#pragma unroll
  for (int i = 0; i < 8; ++i)
#pragma unroll
    for (int j = 0; j < 8; ++j) acc[i][j] = 0.0f;

  for (int s = 0; s < 2; ++s) {
    const float* __restrict__ A = s ? A2 : A1;
    const float* __restrict__ B = s ? B2 : B1;
    for (int k0 = 0; k0 < K; k0 += BKK) {
      __syncthreads();
      const int kk = k0 + lk * 4;
#pragma unroll
      for (int h = 0; h < 2; ++h) {
        const int row = bm + lm + h * 64;
        float4 v = make_float4(0.f, 0.f, 0.f, 0.f);
        if (row < Nrows && kk + 4 <= K)
          v = *reinterpret_cast<const float4*>(A + (size_t)row * K + kk);
        As[lk * 4 + 0][lm + h * 64] = v.x;
        As[lk * 4 + 1][lm + h * 64] = v.y;
        As[lk * 4 + 2][lm + h * 64] = v.z;
        As[lk * 4 + 3][lm + h * 64] = v.w;
      }
#pragma unroll
      for (int h = 0; h < 2; ++h) {
        const int row = bn + lm + h * 64;
        float4 v = make_float4(0.f, 0.f, 0.f, 0.f);
        if (row < J && kk + 4 <= K)
          v = *reinterpret_cast<const float4*>(B + (size_t)row * K + kk);
        Bs[lk * 4 + 0][lm + h * 64] = v.x;
        Bs[lk * 4 + 1][lm + h * 64] = v.y;
        Bs[lk * 4 + 2][lm + h * 64] = v.z;
        Bs[lk * 4 + 3][lm + h * 64] = v.w;
      }
      __syncthreads();
#pragma unroll
      for (int k = 0; k < BKK; ++k) {
        float a[8], b[8];
#pragma unroll
        for (int i = 0; i < 8; ++i) a[i] = As[k][tr * 8 + i];
#pragma unroll
        for (int j = 0; j < 4; ++j) {
          b[j]     = Bs[k][tc * 4 + j];
          b[4 + j] = Bs[k][64 + tc * 4 + j];
        }
#pragma unroll
        for (int i = 0; i < 8; ++i)
#pragma unroll
          for (int j = 0; j < 8; ++j)
            acc[i][j] = fmaf(a[i], b[j], acc[i][j]);
      }
    }
  }

  const int c0 = bn + tc * 4;
  const int c1 = bn + 64 + tc * 4;
  const float4 bb0 = *reinterpret_cast<const float4*>(bias + c0);
  const float4 bb1 = *reinterpret_cast<const float4*>(bias + c1);
#pragma unroll
  for (int i = 0; i < 8; ++i) {
    const int row = bm + tr * 8 + i;
    if (row >= Nrows) continue;
    float4 v0, v1;
    v0.x = acc[i][0] + bb0.x; v0.y = acc[i][1] + bb0.y;
    v0.z = acc[i][2] + bb0.z; v0.w = acc[i][3] + bb0.w;
    v1.x = acc[i][4] + bb1.x; v1.y = acc[i][5] + bb1.y;
    v1.z = acc[i][6] + bb1.z; v1.w = acc[i][7] + bb1.w;
    if (relu) {
      v0.x = fmaxf(v0.x, 0.f); v0.y = fmaxf(v0.y, 0.f);
      v0.z = fmaxf(v0.z, 0.f); v0.w = fmaxf(v0.w, 0.f);
      v1.x = fmaxf(v1.x, 0.f); v1.y = fmaxf(v1.y, 0.f);
      v1.z = fmaxf(v1.z, 0.f); v1.w = fmaxf(v1.w, 0.f);
    }
    *reinterpret_cast<float4*>(Cout + (size_t)row * J + c0) = v0;
    *reinterpret_cast<float4*>(Cout + (size_t)row * J + c1) = v1;
  }
}

// ---------------- layer 3 (J=7): one wave per node ----------------
__global__ __launch_bounds__(256) void layer3_kernel(
    const float* __restrict__ agg, const float* __restrict__ h2,
    const float* __restrict__ wl, const float* __restrict__ wr,
    const float* __restrict__ bias, float* __restrict__ out, int N)
{
  const int gtid = blockIdx.x * blockDim.x + threadIdx.x;
  const int node = gtid >> 6;
  const int lane = threadIdx.x & 63;
  if (node >= N) return;
  const float4 a4 = *reinterpret_cast<const float4*>(agg + (size_t)node * F2 + lane * 4);
  const float4 x4 = *reinterpret_cast<const float4*>(h2 + (size_t)node * F2 + lane * 4);
#pragma unroll
  for (int j = 0; j < F3; ++j) {
    const float4 l4 = *reinterpret_cast<const float4*>(wl + j * F2 + lane * 4);
    const float4 r4 = *reinterpret_cast<const float4*>(wr + j * F2 + lane * 4);
    float t = (a4.x * l4.x + a4.y * l4.y + a4.z * l4.z + a4.w * l4.w)
            + (x4.x * r4.x + x4.y * r4.y + x4.z * r4.z + x4.w * r4.w);
#pragma unroll
    for (int m = 1; m < 64; m <<= 1) t += __shfl_xor(t, m, 64);
    if (lane == 0) out[(size_t)node * F3 + j] = t + bias[j];
  }
}

extern "C" void kernel_launch(void* const* d_in, const int* in_sizes, int n_in,
                              void* d_out, int out_size, void* d_ws, size_t ws_size,
                              hipStream_t stream) {
  const float* x    = (const float*)d_in[0];
  const int*   ei   = (const int*)d_in[1];
  const float* w_l1 = (const float*)d_in[2];
  const float* w_r1 = (const float*)d_in[3];
  const float* b1   = (const float*)d_in[4];
  const float* w_l2 = (const float*)d_in[5];
  const float* w_r2 = (const float*)d_in[6];
  const float* b2   = (const float*)d_in[7];
  const float* w_l3 = (const float*)d_in[8];
  const float* w_r3 = (const float*)d_in[9];
  const float* b3   = (const float*)d_in[10];
  float* out = (float*)d_out;

  const int E = in_sizes[1] / 2;
  const int* src = ei;
  const int* dst = ei + E;

  // workspace layout:
  // ints: row_ptr[N+1] | cnt/cursor[N] | csr_src[E]
  // floats: agg[N*512] | h1[N*512] | h2[N*256]
  int* row_ptr = (int*)d_ws;
  int* cnt     = row_ptr + (N_NODES + 1);
  int* csr_src = cnt + N_NODES;
  float* agg   = (float*)(csr_src + E);
  float* h1    = agg + (size_t)N_NODES * 512;
  float* h2    = h1 + (size_t)N_NODES * 512;

  // ---- CSR build
  hipMemsetAsync(cnt, 0, N_NODES * sizeof(int), stream);
  degree_kernel<<<cdiv_i(E, 256), 256, 0, stream>>>(dst, cnt, E);
  scan_kernel<<<1, 1024, 0, stream>>>(cnt, row_ptr, N_NODES);
  cursor_init_kernel<<<cdiv_i(N_NODES, 256), 256, 0, stream>>>(row_ptr, cnt, N_NODES);
  fill_kernel<<<cdiv_i(E, 256), 256, 0, stream>>>(src, dst, cnt, csr_src, E);

  // ---- layer 1
  gather_mean<F0, 128><<<cdiv_i(N_NODES, 2), 256, 0, stream>>>(x, row_ptr, csr_src, agg, N_NODES);
  {
    dim3 g(cdiv_i(N_NODES, BM), F1 / BN);
    gemm_dual<<<g, 256, 0, stream>>>(agg, x, w_l1, w_r1, b1, h1, N_NODES, F0, F1, 1);
  }

  // ---- layer 2
  gather_mean<F1, 128><<<cdiv_i(N_NODES, 2), 256, 0, stream>>>(h1, row_ptr, csr_src, agg, N_NODES);
  {
    dim3 g(cdiv_i(N_NODES, BM), F2 / BN);
    gemm_dual<<<g, 256, 0, stream>>>(agg, h1, w_l2, w_r2, b2, h2, N_NODES, F1, F2, 1);
  }

  // ---- layer 3
  gather_mean<F2, 64><<<cdiv_i(N_NODES, 4), 256, 0, stream>>>(h2, row_ptr, csr_src, agg, N_NODES);
  layer3_kernel<<<cdiv_i(N_NODES, 4), 256, 0, stream>>>(agg, h2, w_l3, w_r3, b3, out, N_NODES);
}

// Round 3
// 841.062 us; speedup vs baseline: 21.1747x; 3.5687x over previous
//
#include <hip/hip_runtime.h>
#include <cstdint>
#include <cstddef>

#define N_NODES 89250
#define M_PAD   89344   // 698 * 128
#define F0 500
#define F1 512
#define F2 256
#define F3 7
#define KP 512          // padded K for both GEMM passes

typedef __attribute__((ext_vector_type(8))) short bf16x8;   // 8 bf16 = 4 VGPRs
typedef __attribute__((ext_vector_type(4))) float f32x4;

static inline int cdiv_i(int a, int b) { return (a + b - 1) / b; }

__device__ __forceinline__ unsigned short f2b(float f) {
  unsigned int u = __float_as_uint(f);
  u = (u + 0x7FFFu + ((u >> 16) & 1u)) >> 16;
  return (unsigned short)u;
}
__device__ __forceinline__ float b2f(unsigned short h) {
  return __uint_as_float(((unsigned int)h) << 16);
}

// ---------------- CSR build ----------------
__global__ void degree_kernel(const int* __restrict__ dst, int* __restrict__ cnt, int E) {
  int stride = gridDim.x * blockDim.x;
  for (int i = blockIdx.x * blockDim.x + threadIdx.x; i < E; i += stride)
    atomicAdd(&cnt[dst[i]], 1);
}

__global__ __launch_bounds__(1024) void scan_partial(const int* __restrict__ cnt,
                                                     int* __restrict__ row_ptr,
                                                     int* __restrict__ bsum, int n) {
  __shared__ int sm[1024];
  const int i = blockIdx.x * 1024 + threadIdx.x;
  const int v = (i < n) ? cnt[i] : 0;
  sm[threadIdx.x] = v;
  __syncthreads();
  for (int off = 1; off < 1024; off <<= 1) {
    int t = (threadIdx.x >= off) ? sm[threadIdx.x - off] : 0;
    __syncthreads();
    sm[threadIdx.x] += t;
    __syncthreads();
  }
  if (i < n) row_ptr[i] = sm[threadIdx.x] - v;    // block-local exclusive
  if (threadIdx.x == 1023) bsum[blockIdx.x] = sm[1023];
}

__global__ __launch_bounds__(1024) void scan_bsums(int* __restrict__ bsum, int nb) {
  __shared__ int sm[1024];
  const int v = (threadIdx.x < nb) ? bsum[threadIdx.x] : 0;
  sm[threadIdx.x] = v;
  __syncthreads();
  for (int off = 1; off < 1024; off <<= 1) {
    int t = (threadIdx.x >= off) ? sm[threadIdx.x - off] : 0;
    __syncthreads();
    sm[threadIdx.x] += t;
    __syncthreads();
  }
  if (threadIdx.x < nb) bsum[threadIdx.x] = sm[threadIdx.x] - v;  // exclusive
}

__global__ __launch_bounds__(1024) void scan_add(int* __restrict__ row_ptr,
                                                 const int* __restrict__ bsum,
                                                 int n, int total) {
  const int i = blockIdx.x * 1024 + threadIdx.x;
  if (i < n) row_ptr[i] += bsum[i >> 10];
  if (i == 0) row_ptr[n] = total;
}

__global__ void cursor_init_kernel(const int* __restrict__ row_ptr, int* __restrict__ cursor, int n) {
  int i = blockIdx.x * blockDim.x + threadIdx.x;
  if (i < n) cursor[i] = row_ptr[i];
}

__global__ void fill_kernel(const int* __restrict__ src, const int* __restrict__ dst,
                            int* __restrict__ cursor, int* __restrict__ csr_src, int E) {
  int stride = gridDim.x * blockDim.x;
  for (int i = blockIdx.x * blockDim.x + threadIdx.x; i < E; i += stride) {
    const int p = atomicAdd(&cursor[dst[i]], 1);
    csr_src[p] = src[i];
  }
}

// ---------------- conversions to bf16 ----------------
// x [N,500] f32 -> xb [M_PAD,512] bf16 (zero pad cols & rows)
__global__ __launch_bounds__(256) void convert_x_kernel(const float* __restrict__ x,
                                                        unsigned short* __restrict__ xb) {
  const long long total = (long long)M_PAD * (KP / 8);
  const long long stride = (long long)gridDim.x * blockDim.x;
  for (long long idx = (long long)blockIdx.x * blockDim.x + threadIdx.x; idx < total; idx += stride) {
    const int node = (int)(idx >> 6);
    const int c8 = ((int)idx & 63) * 8;
    unsigned short r[8];
#pragma unroll
    for (int j = 0; j < 8; ++j) {
      const int c = c8 + j;
      float v = 0.0f;
      if (node < N_NODES && c < F0) v = x[(size_t)node * F0 + c];
      r[j] = f2b(v);
    }
    *reinterpret_cast<uint4*>(xb + (size_t)node * KP + c8) = *reinterpret_cast<const uint4*>(r);
  }
}

// w [J,K] f32 -> wb [J,KP] bf16 (zero pad K)
__global__ __launch_bounds__(256) void convert_w_kernel(const float* __restrict__ w,
                                                        unsigned short* __restrict__ wb,
                                                        int J, int K) {
  const int total = J * KP;
  const int stride = gridDim.x * blockDim.x;
  for (int idx = blockIdx.x * blockDim.x + threadIdx.x; idx < total; idx += stride) {
    const int j = idx >> 9;           // KP = 512
    const int k = idx & (KP - 1);
    wb[idx] = (k < K) ? f2b(w[(size_t)j * K + k]) : (unsigned short)0;
  }
}

// ---------------- gather-mean (bf16 in/out, f32 accum) ----------------
template<int C>
__global__ __launch_bounds__(256) void gather_mean_bf(
    const unsigned short* __restrict__ xb, const int* __restrict__ row_ptr,
    const int* __restrict__ csr_src, unsigned short* __restrict__ aggb)
{
  constexpr int TPN = C / 8;            // threads per node, 16B each
  constexpr int NPB = 256 / TPN;
  const int node = blockIdx.x * NPB + threadIdx.x / TPN;
  const int t = threadIdx.x % TPN;
  if (node >= M_PAD) return;
  if (node >= N_NODES) {                // zero pad rows every call (ws not re-poisoned-safe)
    *reinterpret_cast<uint4*>(aggb + (size_t)node * C + t * 8) = make_uint4(0, 0, 0, 0);
    return;
  }
  const int beg = row_ptr[node];
  const int end = row_ptr[node + 1];
  float acc[8] = {0.f, 0.f, 0.f, 0.f, 0.f, 0.f, 0.f, 0.f};
  int j = beg;
  for (; j + 1 < end; j += 2) {
    const int s0 = csr_src[j];
    const int s1 = csr_src[j + 1];
    const uint4 v0 = *reinterpret_cast<const uint4*>(xb + (size_t)s0 * C + t * 8);
    const uint4 v1 = *reinterpret_cast<const uint4*>(xb + (size_t)s1 * C + t * 8);
    const unsigned int u0[4] = {v0.x, v0.y, v0.z, v0.w};
    const unsigned int u1[4] = {v1.x, v1.y, v1.z, v1.w};
#pragma unroll
    for (int q = 0; q < 4; ++q) {
      acc[2 * q]     += b2f((unsigned short)(u0[q] & 0xFFFF)) + b2f((unsigned short)(u1[q] & 0xFFFF));
      acc[2 * q + 1] += b2f((unsigned short)(u0[q] >> 16))    + b2f((unsigned short)(u1[q] >> 16));
    }
  }
  if (j < end) {
    const int s0 = csr_src[j];
    const uint4 v0 = *reinterpret_cast<const uint4*>(xb + (size_t)s0 * C + t * 8);
    const unsigned int u0[4] = {v0.x, v0.y, v0.z, v0.w};
#pragma unroll
    for (int q = 0; q < 4; ++q) {
      acc[2 * q]     += b2f((unsigned short)(u0[q] & 0xFFFF));
      acc[2 * q + 1] += b2f((unsigned short)(u0[q] >> 16));
    }
  }
  const int deg = end - beg;
  const float inv = 1.0f / (float)(deg > 1 ? deg : 1);
  unsigned short r[8];
#pragma unroll
  for (int q = 0; q < 8; ++q) r[q] = f2b(acc[q] * inv);
  *reinterpret_cast<uint4*>(aggb + (size_t)node * C + t * 8) = *reinterpret_cast<const uint4*>(r);
}

// ---------------- bf16 MFMA dual GEMM ----------------
// C[row,col] = sum_k A1[row,k]*B1[col,k] + A2[row,k]*B2[col,k] + bias[col]  (+relu)
// A*: [M_PAD, KP] bf16.  B*: [J, KP] bf16.  Cout: [M_PAD, J] bf16.
__global__ __launch_bounds__(256) void gemm_mfma_dual(
    const unsigned short* __restrict__ A1, const unsigned short* __restrict__ A2,
    const unsigned short* __restrict__ B1, const unsigned short* __restrict__ B2,
    const float* __restrict__ bias, unsigned short* __restrict__ Cout,
    int J, int relu)
{
  __shared__ __align__(16) unsigned short Alds[128 * 64];
  __shared__ __align__(16) unsigned short Blds[128 * 64];
  const int tid = threadIdx.x;
  const int lane = tid & 63;
  const int wid = tid >> 6;          // 4 waves
  const int brow = blockIdx.x * 128;
  const int bcol = blockIdx.y * 128;
  const int wr = wid >> 1;           // wave's 64x64 quadrant
  const int wc = wid & 1;

  f32x4 acc[4][4];
#pragma unroll
  for (int m = 0; m < 4; ++m)
#pragma unroll
    for (int n = 0; n < 4; ++n) acc[m][n] = (f32x4){0.f, 0.f, 0.f, 0.f};

  const int srow = lane >> 3;        // staging: 8 lanes per 128B row
  const int scol = (lane & 7) * 8;   // elem offset within row
  const int fr = lane & 15;          // fragment row/col
  const int fk = lane >> 4;          // fragment k-group (8 elems each)

  for (int it = 0; it < 16; ++it) {
    const unsigned short* __restrict__ A = (it < 8) ? A1 : A2;
    const unsigned short* __restrict__ B = (it < 8) ? B1 : B2;
    const int k0 = (it & 7) * 64;
    __syncthreads();                 // previous tile's reads done before overwrite
#pragma unroll
    for (int i = 0; i < 4; ++i) {
      const int r = i * 32 + wid * 8;   // 8-row stripe per wave per iter
      __builtin_amdgcn_global_load_lds(
          (const __attribute__((address_space(1))) unsigned int*)(A + (size_t)(brow + r + srow) * KP + k0 + scol),
          (__attribute__((address_space(3))) unsigned int*)(&Alds[r * 64]),
          16, 0, 0);
      __builtin_amdgcn_global_load_lds(
          (const __attribute__((address_space(1))) unsigned int*)(B + (size_t)(bcol + r + srow) * KP + k0 + scol),
          (__attribute__((address_space(3))) unsigned int*)(&Blds[r * 64]),
          16, 0, 0);
    }
    __syncthreads();                 // staging visible (compiler drains vmcnt)
#pragma unroll
    for (int ks = 0; ks < 2; ++ks) {
      bf16x8 a[4], b[4];
#pragma unroll
      for (int m = 0; m < 4; ++m)
        a[m] = *reinterpret_cast<const bf16x8*>(&Alds[(wr * 64 + m * 16 + fr) * 64 + ks * 32 + fk * 8]);
#pragma unroll
      for (int n = 0; n < 4; ++n)
        b[n] = *reinterpret_cast<const bf16x8*>(&Blds[(wc * 64 + n * 16 + fr) * 64 + ks * 32 + fk * 8]);
#pragma unroll
      for (int m = 0; m < 4; ++m)
#pragma unroll
        for (int n = 0; n < 4; ++n)
          acc[m][n] = __builtin_amdgcn_mfma_f32_16x16x32_bf16(a[m], b[n], acc[m][n], 0, 0, 0);
    }
  }

  // epilogue: C/D layout col=lane&15, row=(lane>>4)*4+i  [m89-verified]
  const int crow0 = brow + wr * 64 + (lane >> 4) * 4;
  const int ccol0 = bcol + wc * 64 + (lane & 15);
#pragma unroll
  for (int n = 0; n < 4; ++n) {
    const int col = ccol0 + n * 16;
    const float bv = bias[col];
#pragma unroll
    for (int m = 0; m < 4; ++m) {
#pragma unroll
      for (int i = 0; i < 4; ++i) {
        const int row = crow0 + m * 16 + i;
        float v = acc[m][n][i] + bv;
        if (relu) v = fmaxf(v, 0.0f);
        Cout[(size_t)row * J + col] = f2b(v);
      }
    }
  }
}

// ---------------- layer 3 (J=7): one wave per node ----------------
__global__ __launch_bounds__(256) void layer3_kernel(
    const unsigned short* __restrict__ aggb, const unsigned short* __restrict__ h2b,
    const float* __restrict__ wl, const float* __restrict__ wr,
    const float* __restrict__ bias, float* __restrict__ out, int N)
{
  const int gtid = blockIdx.x * blockDim.x + threadIdx.x;
  const int node = gtid >> 6;
  const int lane = threadIdx.x & 63;
  if (node >= N) return;
  const uint2 au = *reinterpret_cast<const uint2*>(aggb + (size_t)node * F2 + lane * 4);
  const uint2 xu = *reinterpret_cast<const uint2*>(h2b + (size_t)node * F2 + lane * 4);
  const float a0 = b2f((unsigned short)(au.x & 0xFFFF)), a1 = b2f((unsigned short)(au.x >> 16));
  const float a2 = b2f((unsigned short)(au.y & 0xFFFF)), a3 = b2f((unsigned short)(au.y >> 16));
  const float x0 = b2f((unsigned short)(xu.x & 0xFFFF)), x1 = b2f((unsigned short)(xu.x >> 16));
  const float x2 = b2f((unsigned short)(xu.y & 0xFFFF)), x3 = b2f((unsigned short)(xu.y >> 16));
#pragma unroll
  for (int j = 0; j < F3; ++j) {
    const float4 l4 = *reinterpret_cast<const float4*>(wl + j * F2 + lane * 4);
    const float4 r4 = *reinterpret_cast<const float4*>(wr + j * F2 + lane * 4);
    float t = a0 * l4.x + a1 * l4.y + a2 * l4.z + a3 * l4.w
            + x0 * r4.x + x1 * r4.y + x2 * r4.z + x3 * r4.w;
#pragma unroll
    for (int m = 1; m < 64; m <<= 1) t += __shfl_xor(t, m, 64);
    if (lane == 0) out[(size_t)node * F3 + j] = t + bias[j];
  }
}

extern "C" void kernel_launch(void* const* d_in, const int* in_sizes, int n_in,
                              void* d_out, int out_size, void* d_ws, size_t ws_size,
                              hipStream_t stream) {
  const float* x    = (const float*)d_in[0];
  const int*   ei   = (const int*)d_in[1];
  const float* w_l1 = (const float*)d_in[2];
  const float* w_r1 = (const float*)d_in[3];
  const float* b1   = (const float*)d_in[4];
  const float* w_l2 = (const float*)d_in[5];
  const float* w_r2 = (const float*)d_in[6];
  const float* b2   = (const float*)d_in[7];
  const float* w_l3 = (const float*)d_in[8];
  const float* w_r3 = (const float*)d_in[9];
  const float* b3   = (const float*)d_in[10];
  float* out = (float*)d_out;

  const int E = in_sizes[1] / 2;
  const int* src = ei;
  const int* dst = ei + E;

  // ---- workspace carve-up
  char* p = (char*)d_ws;
  int* row_ptr = (int*)p;           p += (size_t)(N_NODES + 1) * 4;
  int* cnt     = (int*)p;           p += (size_t)N_NODES * 4;
  int* bsum    = (int*)p;           p += 1024 * 4;
  int* csr_src = (int*)p;           p += (size_t)E * 4;
  p = (char*)(((uintptr_t)p + 255) & ~(uintptr_t)255);
  unsigned short* xb   = (unsigned short*)p;  p += (size_t)M_PAD * KP * 2;
  unsigned short* aggb = (unsigned short*)p;  p += (size_t)M_PAD * KP * 2;
  unsigned short* h1b  = (unsigned short*)p;  p += (size_t)M_PAD * KP * 2;
  unsigned short* h2b  = (unsigned short*)p;  p += (size_t)M_PAD * F2 * 2;
  unsigned short* wl1b = (unsigned short*)p;  p += (size_t)F1 * KP * 2;
  unsigned short* wr1b = (unsigned short*)p;  p += (size_t)F1 * KP * 2;
  unsigned short* wl2b = (unsigned short*)p;  p += (size_t)F2 * KP * 2;
  unsigned short* wr2b = (unsigned short*)p;  p += (size_t)F2 * KP * 2;

  const int nb = cdiv_i(N_NODES, 1024);   // 88

  // ---- CSR build
  hipMemsetAsync(cnt, 0, (size_t)N_NODES * sizeof(int), stream);
  degree_kernel<<<cdiv_i(E, 256), 256, 0, stream>>>(dst, cnt, E);
  scan_partial<<<nb, 1024, 0, stream>>>(cnt, row_ptr, bsum, N_NODES);
  scan_bsums<<<1, 1024, 0, stream>>>(bsum, nb);
  scan_add<<<nb, 1024, 0, stream>>>(row_ptr, bsum, N_NODES, E);
  cursor_init_kernel<<<cdiv_i(N_NODES, 256), 256, 0, stream>>>(row_ptr, cnt, N_NODES);
  fill_kernel<<<cdiv_i(E, 256), 256, 0, stream>>>(src, dst, cnt, csr_src, E);

  // ---- conversions
  convert_x_kernel<<<2048, 256, 0, stream>>>(x, xb);
  convert_w_kernel<<<512, 256, 0, stream>>>(w_l1, wl1b, F1, F0);
  convert_w_kernel<<<512, 256, 0, stream>>>(w_r1, wr1b, F1, F0);
  convert_w_kernel<<<256, 256, 0, stream>>>(w_l2, wl2b, F2, F1);
  convert_w_kernel<<<256, 256, 0, stream>>>(w_r2, wr2b, F2, F1);

  // ---- layer 1: agg = mean-gather(x);  h1 = relu(agg@wl1.T + x@wr1.T + b1)
  gather_mean_bf<512><<<cdiv_i(M_PAD, 4), 256, 0, stream>>>(xb, row_ptr, csr_src, aggb);
  {
    dim3 g(M_PAD / 128, F1 / 128);
    gemm_mfma_dual<<<g, 256, 0, stream>>>(aggb, xb, wl1b, wr1b, b1, h1b, F1, 1);
  }

  // ---- layer 2
  gather_mean_bf<512><<<cdiv_i(M_PAD, 4), 256, 0, stream>>>(h1b, row_ptr, csr_src, aggb);
  {
    dim3 g(M_PAD / 128, F2 / 128);
    gemm_mfma_dual<<<g, 256, 0, stream>>>(aggb, h1b, wl2b, wr2b, b2, h2b, F2, 1);
  }

  // ---- layer 3 (reuse aggb as [M_PAD, 256])
  gather_mean_bf<256><<<cdiv_i(M_PAD, 8), 256, 0, stream>>>(h2b, row_ptr, csr_src, aggb);
  layer3_kernel<<<cdiv_i(N_NODES * 64, 256), 256, 0, stream>>>(aggb, h2b, w_l3, w_r3, b3, out, N_NODES);
}

// Round 4
// 707.314 us; speedup vs baseline: 25.1786x; 1.1891x over previous
//
#include <hip/hip_runtime.h>
#include <cstdint>
#include <cstddef>

#define N_NODES 89250
#define M_PAD   89344   // 698 * 128
#define F0 500
#define F1 512
#define F2 256
#define F3 7
#define KP 512          // padded K for the MFMA GEMMs

typedef __attribute__((ext_vector_type(8))) short bf16x8;   // 8 bf16 = 4 VGPRs
typedef __attribute__((ext_vector_type(4))) float f32x4;

static inline int cdiv_i(int a, int b) { return (a + b - 1) / b; }

__device__ __forceinline__ unsigned short f2b(float f) {
  unsigned int u = __float_as_uint(f);
  u = (u + 0x7FFFu + ((u >> 16) & 1u)) >> 16;
  return (unsigned short)u;
}
__device__ __forceinline__ float b2f(unsigned short h) {
  return __uint_as_float(((unsigned int)h) << 16);
}

// ---------------- CSR build ----------------
__global__ void degree_kernel(const int* __restrict__ dst, int* __restrict__ cnt, int E) {
  int stride = gridDim.x * blockDim.x;
  for (int i = blockIdx.x * blockDim.x + threadIdx.x; i < E; i += stride)
    atomicAdd(&cnt[dst[i]], 1);
}

__global__ __launch_bounds__(1024) void scan_partial(const int* __restrict__ cnt,
                                                     int* __restrict__ row_ptr,
                                                     int* __restrict__ bsum, int n) {
  __shared__ int sm[1024];
  const int i = blockIdx.x * 1024 + threadIdx.x;
  const int v = (i < n) ? cnt[i] : 0;
  sm[threadIdx.x] = v;
  __syncthreads();
  for (int off = 1; off < 1024; off <<= 1) {
    int t = (threadIdx.x >= off) ? sm[threadIdx.x - off] : 0;
    __syncthreads();
    sm[threadIdx.x] += t;
    __syncthreads();
  }
  if (i < n) row_ptr[i] = sm[threadIdx.x] - v;    // block-local exclusive
  if (threadIdx.x == 1023) bsum[blockIdx.x] = sm[1023];
}

__global__ __launch_bounds__(1024) void scan_bsums(int* __restrict__ bsum, int nb) {
  __shared__ int sm[1024];
  const int v = (threadIdx.x < nb) ? bsum[threadIdx.x] : 0;
  sm[threadIdx.x] = v;
  __syncthreads();
  for (int off = 1; off < 1024; off <<= 1) {
    int t = (threadIdx.x >= off) ? sm[threadIdx.x - off] : 0;
    __syncthreads();
    sm[threadIdx.x] += t;
    __syncthreads();
  }
  if (threadIdx.x < nb) bsum[threadIdx.x] = sm[threadIdx.x] - v;  // exclusive
}

__global__ __launch_bounds__(1024) void scan_add(int* __restrict__ row_ptr,
                                                 const int* __restrict__ bsum,
                                                 int n, int total) {
  const int i = blockIdx.x * 1024 + threadIdx.x;
  if (i < n) row_ptr[i] += bsum[i >> 10];
  if (i == 0) row_ptr[n] = total;
}

__global__ void cursor_init_kernel(const int* __restrict__ row_ptr, int* __restrict__ cursor, int n) {
  int i = blockIdx.x * blockDim.x + threadIdx.x;
  if (i < n) cursor[i] = row_ptr[i];
}

__global__ void fill_kernel(const int* __restrict__ src, const int* __restrict__ dst,
                            int* __restrict__ cursor, int* __restrict__ csr_src, int E) {
  int stride = gridDim.x * blockDim.x;
  for (int i = blockIdx.x * blockDim.x + threadIdx.x; i < E; i += stride) {
    const int p = atomicAdd(&cursor[dst[i]], 1);
    csr_src[p] = src[i];
  }
}

// ---------------- conversions to bf16 ----------------
__global__ __launch_bounds__(256) void convert_x_kernel(const float* __restrict__ x,
                                                        unsigned short* __restrict__ xb) {
  const long long total = (long long)M_PAD * (KP / 8);
  const long long stride = (long long)gridDim.x * blockDim.x;
  for (long long idx = (long long)blockIdx.x * blockDim.x + threadIdx.x; idx < total; idx += stride) {
    const int node = (int)(idx >> 6);
    const int c8 = ((int)idx & 63) * 8;
    unsigned short r[8];
#pragma unroll
    for (int j = 0; j < 8; ++j) {
      const int c = c8 + j;
      float v = 0.0f;
      if (node < N_NODES && c < F0) v = x[(size_t)node * F0 + c];
      r[j] = f2b(v);
    }
    *reinterpret_cast<uint4*>(xb + (size_t)node * KP + c8) = *reinterpret_cast<const uint4*>(r);
  }
}

// w [J,K] f32 -> wb [J,KP] bf16 (zero pad K)
__global__ __launch_bounds__(256) void convert_w_kernel(const float* __restrict__ w,
                                                        unsigned short* __restrict__ wb,
                                                        int J, int K) {
  const int total = J * KP;
  const int stride = gridDim.x * blockDim.x;
  for (int idx = blockIdx.x * blockDim.x + threadIdx.x; idx < total; idx += stride) {
    const int j = idx >> 9;           // KP = 512
    const int k = idx & (KP - 1);
    wb[idx] = (k < K) ? f2b(w[(size_t)j * K + k]) : (unsigned short)0;
  }
}

// ---------------- gather-mean (bf16 in/out, f32 accum), C=512, wave per node ----------------
__global__ __launch_bounds__(256) void gather_mean_bf512(
    const unsigned short* __restrict__ xb, const int* __restrict__ row_ptr,
    const int* __restrict__ csr_src, unsigned short* __restrict__ aggb)
{
  const int node = blockIdx.x * 4 + (threadIdx.x >> 6);
  const int t = threadIdx.x & 63;
  if (node >= M_PAD) return;
  if (node >= N_NODES) {                // zero pad rows (ws is not zeroed between replays)
    *reinterpret_cast<uint4*>(aggb + (size_t)node * 512 + t * 8) = make_uint4(0, 0, 0, 0);
    return;
  }
  const int beg = row_ptr[node];
  const int end = row_ptr[node + 1];
  float acc[8] = {0.f, 0.f, 0.f, 0.f, 0.f, 0.f, 0.f, 0.f};
  int j = beg;
  for (; j + 1 < end; j += 2) {
    const int s0 = csr_src[j];
    const int s1 = csr_src[j + 1];
    const uint4 v0 = *reinterpret_cast<const uint4*>(xb + (size_t)s0 * 512 + t * 8);
    const uint4 v1 = *reinterpret_cast<const uint4*>(xb + (size_t)s1 * 512 + t * 8);
    const unsigned int u0[4] = {v0.x, v0.y, v0.z, v0.w};
    const unsigned int u1[4] = {v1.x, v1.y, v1.z, v1.w};
#pragma unroll
    for (int q = 0; q < 4; ++q) {
      acc[2 * q]     += b2f((unsigned short)(u0[q] & 0xFFFF)) + b2f((unsigned short)(u1[q] & 0xFFFF));
      acc[2 * q + 1] += b2f((unsigned short)(u0[q] >> 16))    + b2f((unsigned short)(u1[q] >> 16));
    }
  }
  if (j < end) {
    const int s0 = csr_src[j];
    const uint4 v0 = *reinterpret_cast<const uint4*>(xb + (size_t)s0 * 512 + t * 8);
    const unsigned int u0[4] = {v0.x, v0.y, v0.z, v0.w};
#pragma unroll
    for (int q = 0; q < 4; ++q) {
      acc[2 * q]     += b2f((unsigned short)(u0[q] & 0xFFFF));
      acc[2 * q + 1] += b2f((unsigned short)(u0[q] >> 16));
    }
  }
  const int deg = end - beg;
  const float inv = 1.0f / (float)(deg > 1 ? deg : 1);
  unsigned short r[8];
#pragma unroll
  for (int q = 0; q < 8; ++q) r[q] = f2b(acc[q] * inv);
  *reinterpret_cast<uint4*>(aggb + (size_t)node * 512 + t * 8) = *reinterpret_cast<const uint4*>(r);
}

// ---------------- bf16 MFMA GEMM (optionally dual-A/B), T1 XCD swizzle + T2 LDS swizzle ----------------
// niter=16: C = A1@B1.T + A2@B2.T (K=512 each);  niter=8: C = A1@B1.T.
// fuse=1: C = relu-optional(C + bias). All A/B rows bf16 with row stride KP=512.
__global__ __launch_bounds__(256) void gemm_mfma(
    const unsigned short* __restrict__ A1, const unsigned short* __restrict__ A2,
    const unsigned short* __restrict__ B1, const unsigned short* __restrict__ B2,
    const float* __restrict__ bias, unsigned short* __restrict__ Cout,
    int J, int niter, int fuse, int relu)
{
  __shared__ __align__(16) unsigned short Alds[128 * 64];
  __shared__ __align__(16) unsigned short Blds[128 * 64];
  const int tid = threadIdx.x;
  const int lane = tid & 63;
  const int wid = tid >> 6;          // 4 waves

  // T1: bijective XCD swizzle over the flat grid (nwg % 8 == 0 by construction)
  const int nwg = gridDim.x * gridDim.y;
  int wg = blockIdx.y * gridDim.x + blockIdx.x;
  const int cpx = nwg >> 3;
  wg = (wg & 7) * cpx + (wg >> 3);
  const int brow = (wg % gridDim.x) * 128;
  const int bcol = (wg / gridDim.x) * 128;

  const int wr = wid >> 1;           // wave's 64x64 quadrant
  const int wc = wid & 1;

  f32x4 acc[4][4];
#pragma unroll
  for (int m = 0; m < 4; ++m)
#pragma unroll
    for (int n = 0; n < 4; ++n) acc[m][n] = (f32x4){0.f, 0.f, 0.f, 0.f};

  const int srow = lane >> 3;            // 0..7: row within 8-row stripe
  const int gchunk = (lane & 7) ^ srow;  // T2: pre-swizzled source 16B-chunk
  const int fr = lane & 15;              // fragment row/col
  const int fk = lane >> 4;              // fragment k-group (8 elems)

  for (int it = 0; it < niter; ++it) {
    const unsigned short* __restrict__ A = (it < 8) ? A1 : A2;
    const unsigned short* __restrict__ B = (it < 8) ? B1 : B2;
    const int k0 = (it & 7) * 64;
    __syncthreads();                 // previous tile's reads done before overwrite
#pragma unroll
    for (int i = 0; i < 4; ++i) {
      const int r = i * 32 + wid * 8;   // 8-row stripe per wave per iter
      __builtin_amdgcn_global_load_lds(
          (const __attribute__((address_space(1))) unsigned int*)(A + (size_t)(brow + r + srow) * KP + k0 + gchunk * 8),
          (__attribute__((address_space(3))) unsigned int*)(&Alds[r * 64]),
          16, 0, 0);
      __builtin_amdgcn_global_load_lds(
          (const __attribute__((address_space(1))) unsigned int*)(B + (size_t)(bcol + r + srow) * KP + k0 + gchunk * 8),
          (__attribute__((address_space(3))) unsigned int*)(&Blds[r * 64]),
          16, 0, 0);
    }
    __syncthreads();                 // staging visible (compiler drains vmcnt)
#pragma unroll
    for (int ks = 0; ks < 2; ++ks) {
      bf16x8 a[4], b[4];
#pragma unroll
      for (int m = 0; m < 4; ++m) {
        const int row = wr * 64 + m * 16 + fr;
        a[m] = *reinterpret_cast<const bf16x8*>(&Alds[row * 64 + (((ks * 4 + fk) ^ (fr & 7)) * 8)]);
      }
#pragma unroll
      for (int n = 0; n < 4; ++n) {
        const int row = wc * 64 + n * 16 + fr;
        b[n] = *reinterpret_cast<const bf16x8*>(&Blds[row * 64 + (((ks * 4 + fk) ^ (fr & 7)) * 8)]);
      }
#pragma unroll
      for (int m = 0; m < 4; ++m)
#pragma unroll
        for (int n = 0; n < 4; ++n)
          acc[m][n] = __builtin_amdgcn_mfma_f32_16x16x32_bf16(a[m], b[n], acc[m][n], 0, 0, 0);
    }
  }

  // epilogue: C/D layout col=lane&15, row=(lane>>4)*4+i  [m89-verified]
  const int crow0 = brow + wr * 64 + (lane >> 4) * 4;
  const int ccol0 = bcol + wc * 64 + (lane & 15);
#pragma unroll
  for (int n = 0; n < 4; ++n) {
    const int col = ccol0 + n * 16;
    const float bv = fuse ? bias[col] : 0.0f;
#pragma unroll
    for (int m = 0; m < 4; ++m) {
#pragma unroll
      for (int i = 0; i < 4; ++i) {
        const int row = crow0 + m * 16 + i;
        float v = acc[m][n][i] + bv;
        if (relu) v = fmaxf(v, 0.0f);
        Cout[(size_t)row * J + col] = f2b(v);
      }
    }
  }
}

// ---------------- combine layer 2: h2 = relu(mean-gather(y2[:, :256]) + y2[i, 256:] + b2) ----------------
__global__ __launch_bounds__(256) void combine2_kernel(
    const unsigned short* __restrict__ y, const int* __restrict__ row_ptr,
    const int* __restrict__ csr_src, const float* __restrict__ bias,
    unsigned short* __restrict__ h)
{
  const int node = blockIdx.x * 8 + (threadIdx.x >> 5);
  const int t = threadIdx.x & 31;        // 8 channels each -> 256
  if (node >= N_NODES) return;
  const int beg = row_ptr[node];
  const int end = row_ptr[node + 1];
  float acc[8] = {0.f, 0.f, 0.f, 0.f, 0.f, 0.f, 0.f, 0.f};
  int j = beg;
  for (; j + 1 < end; j += 2) {
    const int s0 = csr_src[j];
    const int s1 = csr_src[j + 1];
    const uint4 v0 = *reinterpret_cast<const uint4*>(y + (size_t)s0 * 512 + t * 8);
    const uint4 v1 = *reinterpret_cast<const uint4*>(y + (size_t)s1 * 512 + t * 8);
    const unsigned int u0[4] = {v0.x, v0.y, v0.z, v0.w};
    const unsigned int u1[4] = {v1.x, v1.y, v1.z, v1.w};
#pragma unroll
    for (int q = 0; q < 4; ++q) {
      acc[2 * q]     += b2f((unsigned short)(u0[q] & 0xFFFF)) + b2f((unsigned short)(u1[q] & 0xFFFF));
      acc[2 * q + 1] += b2f((unsigned short)(u0[q] >> 16))    + b2f((unsigned short)(u1[q] >> 16));
    }
  }
  if (j < end) {
    const int s0 = csr_src[j];
    const uint4 v0 = *reinterpret_cast<const uint4*>(y + (size_t)s0 * 512 + t * 8);
    const unsigned int u0[4] = {v0.x, v0.y, v0.z, v0.w};
#pragma unroll
    for (int q = 0; q < 4; ++q) {
      acc[2 * q]     += b2f((unsigned short)(u0[q] & 0xFFFF));
      acc[2 * q + 1] += b2f((unsigned short)(u0[q] >> 16));
    }
  }
  const int deg = end - beg;
  const float inv = 1.0f / (float)(deg > 1 ? deg : 1);
  const uint4 rv = *reinterpret_cast<const uint4*>(y + (size_t)node * 512 + 256 + t * 8);
  const unsigned int ru[4] = {rv.x, rv.y, rv.z, rv.w};
  unsigned short r[8];
#pragma unroll
  for (int q = 0; q < 4; ++q) {
    const float y0 = b2f((unsigned short)(ru[q] & 0xFFFF));
    const float y1 = b2f((unsigned short)(ru[q] >> 16));
    const float c0 = acc[2 * q] * inv + y0 + bias[t * 8 + 2 * q];
    const float c1 = acc[2 * q + 1] * inv + y1 + bias[t * 8 + 2 * q + 1];
    r[2 * q]     = f2b(fmaxf(c0, 0.0f));
    r[2 * q + 1] = f2b(fmaxf(c1, 0.0f));
  }
  *reinterpret_cast<uint4*>(h + (size_t)node * 256 + t * 8) = *reinterpret_cast<const uint4*>(r);
}

// ---------------- layer 3 projection: y3[n, 0..6] = h2[n]@wl3.T, y3[n, 8..14] = h2[n]@wr3.T ----------------
__global__ __launch_bounds__(256) void gemm3_node(
    const unsigned short* __restrict__ h2, const float* __restrict__ wl,
    const float* __restrict__ wr, unsigned short* __restrict__ y3, int N)
{
  const int node = (blockIdx.x * 256 + threadIdx.x) >> 6;
  const int lane = threadIdx.x & 63;
  if (node >= N) return;
  const uint2 hu = *reinterpret_cast<const uint2*>(h2 + (size_t)node * F2 + lane * 4);
  const float h0 = b2f((unsigned short)(hu.x & 0xFFFF)), h1 = b2f((unsigned short)(hu.x >> 16));
  const float h2v = b2f((unsigned short)(hu.y & 0xFFFF)), h3 = b2f((unsigned short)(hu.y >> 16));
#pragma unroll
  for (int j = 0; j < F3; ++j) {
    const float4 l4 = *reinterpret_cast<const float4*>(wl + j * F2 + lane * 4);
    const float4 r4 = *reinterpret_cast<const float4*>(wr + j * F2 + lane * 4);
    float tl = h0 * l4.x + h1 * l4.y + h2v * l4.z + h3 * l4.w;
    float tr = h0 * r4.x + h1 * r4.y + h2v * r4.z + h3 * r4.w;
#pragma unroll
    for (int m = 1; m < 64; m <<= 1) {
      tl += __shfl_xor(tl, m, 64);
      tr += __shfl_xor(tr, m, 64);
    }
    if (lane == 0) {
      y3[(size_t)node * 16 + j]     = f2b(tl);
      y3[(size_t)node * 16 + 8 + j] = f2b(tr);
    }
  }
}

// ---------------- combine layer 3: out = mean-gather(y3[:, 0..6]) + y3[i, 8..14] + b3 ----------------
__global__ __launch_bounds__(256) void combine3_kernel(
    const unsigned short* __restrict__ y3, const int* __restrict__ row_ptr,
    const int* __restrict__ csr_src, const float* __restrict__ b3,
    float* __restrict__ out, int N)
{
  const int node = blockIdx.x * 256 + threadIdx.x;
  if (node >= N) return;
  const int beg = row_ptr[node];
  const int end = row_ptr[node + 1];
  float acc[8] = {0.f, 0.f, 0.f, 0.f, 0.f, 0.f, 0.f, 0.f};
  for (int j = beg; j < end; ++j) {
    const int s = csr_src[j];
    const uint4 v = *reinterpret_cast<const uint4*>(y3 + (size_t)s * 16);
    const unsigned int u[4] = {v.x, v.y, v.z, v.w};
#pragma unroll
    for (int q = 0; q < 4; ++q) {
      acc[2 * q]     += b2f((unsigned short)(u[q] & 0xFFFF));
      acc[2 * q + 1] += b2f((unsigned short)(u[q] >> 16));
    }
  }
  const int deg = end - beg;
  const float inv = 1.0f / (float)(deg > 1 ? deg : 1);
  const uint4 rv = *reinterpret_cast<const uint4*>(y3 + (size_t)node * 16 + 8);
  const unsigned int ru[4] = {rv.x, rv.y, rv.z, rv.w};
  float yr[8];
#pragma unroll
  for (int q = 0; q < 4; ++q) {
    yr[2 * q]     = b2f((unsigned short)(ru[q] & 0xFFFF));
    yr[2 * q + 1] = b2f((unsigned short)(ru[q] >> 16));
  }
#pragma unroll
  for (int q = 0; q < F3; ++q)
    out[(size_t)node * F3 + q] = acc[q] * inv + yr[q] + b3[q];
}

extern "C" void kernel_launch(void* const* d_in, const int* in_sizes, int n_in,
                              void* d_out, int out_size, void* d_ws, size_t ws_size,
                              hipStream_t stream) {
  const float* x    = (const float*)d_in[0];
  const int*   ei   = (const int*)d_in[1];
  const float* w_l1 = (const float*)d_in[2];
  const float* w_r1 = (const float*)d_in[3];
  const float* b1   = (const float*)d_in[4];
  const float* w_l2 = (const float*)d_in[5];
  const float* w_r2 = (const float*)d_in[6];
  const float* b2   = (const float*)d_in[7];
  const float* w_l3 = (const float*)d_in[8];
  const float* w_r3 = (const float*)d_in[9];
  const float* b3   = (const float*)d_in[10];
  float* out = (float*)d_out;

  const int E = in_sizes[1] / 2;
  const int* src = ei;
  const int* dst = ei + E;

  // ---- workspace carve-up (peak ~280 MB, below R3's ~326 MB)
  char* p = (char*)d_ws;
  int* row_ptr = (int*)p;           p += (size_t)(N_NODES + 1) * 4;
  int* cnt     = (int*)p;           p += (size_t)N_NODES * 4;
  int* bsum    = (int*)p;           p += 1024 * 4;
  int* csr_src = (int*)p;           p += (size_t)E * 4;
  p = (char*)(((uintptr_t)p + 255) & ~(uintptr_t)255);
  unsigned short* xb   = (unsigned short*)p;  p += (size_t)M_PAD * KP * 2;  // also reused as y2
  unsigned short* aggb = (unsigned short*)p;  p += (size_t)M_PAD * KP * 2;  // also reused as h2
  unsigned short* h1b  = (unsigned short*)p;  p += (size_t)M_PAD * KP * 2;  // also reused as y3
  unsigned short* wl1b = (unsigned short*)p;  p += (size_t)F1 * KP * 2;
  unsigned short* wr1b = (unsigned short*)p;  p += (size_t)F1 * KP * 2;
  unsigned short* w2b  = (unsigned short*)p;  p += (size_t)F1 * KP * 2;     // concat [wl2; wr2] -> 512 rows

  unsigned short* y2  = xb;     // [M_PAD, 512] (cols 0..255 = yl2, 256..511 = yr2); xb dead after GEMM1
  unsigned short* h2b = aggb;   // [M_PAD, 256]; aggb dead after GEMM1
  unsigned short* y3  = h1b;    // [M_PAD, 16];  h1b dead after GEMM2

  const int nb = cdiv_i(N_NODES, 1024);   // 88

  // ---- CSR build
  hipMemsetAsync(cnt, 0, (size_t)N_NODES * sizeof(int), stream);
  degree_kernel<<<cdiv_i(E, 256), 256, 0, stream>>>(dst, cnt, E);
  scan_partial<<<nb, 1024, 0, stream>>>(cnt, row_ptr, bsum, N_NODES);
  scan_bsums<<<1, 1024, 0, stream>>>(bsum, nb);
  scan_add<<<nb, 1024, 0, stream>>>(row_ptr, bsum, N_NODES, E);
  cursor_init_kernel<<<cdiv_i(N_NODES, 256), 256, 0, stream>>>(row_ptr, cnt, N_NODES);
  fill_kernel<<<cdiv_i(E, 256), 256, 0, stream>>>(src, dst, cnt, csr_src, E);

  // ---- conversions
  convert_x_kernel<<<2048, 256, 0, stream>>>(x, xb);
  convert_w_kernel<<<512, 256, 0, stream>>>(w_l1, wl1b, F1, F0);
  convert_w_kernel<<<512, 256, 0, stream>>>(w_r1, wr1b, F1, F0);
  convert_w_kernel<<<256, 256, 0, stream>>>(w_l2, w2b, F2, F1);                   // rows 0..255
  convert_w_kernel<<<256, 256, 0, stream>>>(w_r2, w2b + (size_t)F2 * KP, F2, F1); // rows 256..511

  // ---- layer 1: agg = mean-gather(x);  h1 = relu(agg@wl1.T + x@wr1.T + b1)
  gather_mean_bf512<<<cdiv_i(M_PAD, 4), 256, 0, stream>>>(xb, row_ptr, csr_src, aggb);
  {
    dim3 g(M_PAD / 128, F1 / 128);
    gemm_mfma<<<g, 256, 0, stream>>>(aggb, xb, wl1b, wr1b, b1, h1b, F1, 16, 1, 1);
  }

  // ---- layer 2 (aggregate AFTER projection): y2 = h1 @ [wl2; wr2].T, then combine
  {
    dim3 g(M_PAD / 128, 512 / 128);
    gemm_mfma<<<g, 256, 0, stream>>>(h1b, h1b, w2b, w2b, (const float*)nullptr, y2, 512, 8, 0, 0);
  }
  combine2_kernel<<<cdiv_i(N_NODES, 8), 256, 0, stream>>>(y2, row_ptr, csr_src, b2, h2b);

  // ---- layer 3: project to 7+7, then combine
  gemm3_node<<<cdiv_i(N_NODES * 64, 256), 256, 0, stream>>>(h2b, w_l3, w_r3, y3, N_NODES);
  combine3_kernel<<<cdiv_i(N_NODES, 256), 256, 0, stream>>>(y3, row_ptr, csr_src, b3, out, N_NODES);
}

// Round 5
// 686.405 us; speedup vs baseline: 25.9456x; 1.0305x over previous
//
#include <hip/hip_runtime.h>
#include <cstdint>
#include <cstddef>

#define N_NODES 89250
#define M_PAD   89344   // 698 * 128
#define F0 500
#define F1 512
#define F2 256
#define F3 7
#define KP 512          // padded K for the MFMA GEMMs

typedef __attribute__((ext_vector_type(8))) short bf16x8;   // 8 bf16 = 4 VGPRs
typedef __attribute__((ext_vector_type(4))) float f32x4;
typedef __attribute__((ext_vector_type(4))) unsigned int uintx4;

static inline int cdiv_i(int a, int b) { return (a + b - 1) / b; }

__device__ __forceinline__ unsigned short f2b(float f) {
  unsigned int u = __float_as_uint(f);
  u = (u + 0x7FFFu + ((u >> 16) & 1u)) >> 16;
  return (unsigned short)u;
}
__device__ __forceinline__ float b2f(unsigned short h) {
  return __uint_as_float(((unsigned int)h) << 16);
}

// ---------------- CSR build ----------------
__global__ void degree_kernel(const int* __restrict__ dst, int* __restrict__ cnt, int E) {
  int stride = gridDim.x * blockDim.x;
  for (int i = blockIdx.x * blockDim.x + threadIdx.x; i < E; i += stride)
    atomicAdd(&cnt[dst[i]], 1);
}

__global__ __launch_bounds__(1024) void scan_partial(const int* __restrict__ cnt,
                                                     int* __restrict__ row_ptr,
                                                     int* __restrict__ bsum, int n) {
  __shared__ int sm[1024];
  const int i = blockIdx.x * 1024 + threadIdx.x;
  const int v = (i < n) ? cnt[i] : 0;
  sm[threadIdx.x] = v;
  __syncthreads();
  for (int off = 1; off < 1024; off <<= 1) {
    int t = (threadIdx.x >= off) ? sm[threadIdx.x - off] : 0;
    __syncthreads();
    sm[threadIdx.x] += t;
    __syncthreads();
  }
  if (i < n) row_ptr[i] = sm[threadIdx.x] - v;    // block-local exclusive
  if (threadIdx.x == 1023) bsum[blockIdx.x] = sm[1023];
}

__global__ __launch_bounds__(1024) void scan_bsums(int* __restrict__ bsum, int nb) {
  __shared__ int sm[1024];
  const int v = (threadIdx.x < nb) ? bsum[threadIdx.x] : 0;
  sm[threadIdx.x] = v;
  __syncthreads();
  for (int off = 1; off < 1024; off <<= 1) {
    int t = (threadIdx.x >= off) ? sm[threadIdx.x - off] : 0;
    __syncthreads();
    sm[threadIdx.x] += t;
    __syncthreads();
  }
  if (threadIdx.x < nb) bsum[threadIdx.x] = sm[threadIdx.x] - v;  // exclusive
}

// adds block offsets AND initializes cursor = row_ptr (saves a pass)
__global__ __launch_bounds__(1024) void scan_add(int* __restrict__ row_ptr,
                                                 const int* __restrict__ bsum,
                                                 int* __restrict__ cursor,
                                                 int n, int total) {
  const int i = blockIdx.x * 1024 + threadIdx.x;
  if (i < n) {
    const int v = row_ptr[i] + bsum[i >> 10];
    row_ptr[i] = v;
    cursor[i] = v;
  }
  if (i == 0) row_ptr[n] = total;
}

__global__ void fill_kernel(const int* __restrict__ src, const int* __restrict__ dst,
                            int* __restrict__ cursor, int* __restrict__ csr_src, int E) {
  int stride = gridDim.x * blockDim.x;
  for (int i = blockIdx.x * blockDim.x + threadIdx.x; i < E; i += stride) {
    const int p = atomicAdd(&cursor[dst[i]], 1);
    csr_src[p] = src[i];
  }
}

// ---------------- conversions to bf16 ----------------
__global__ __launch_bounds__(256) void convert_x_kernel(const float* __restrict__ x,
                                                        unsigned short* __restrict__ xb) {
  const long long total = (long long)M_PAD * (KP / 8);
  const long long stride = (long long)gridDim.x * blockDim.x;
  for (long long idx = (long long)blockIdx.x * blockDim.x + threadIdx.x; idx < total; idx += stride) {
    const int node = (int)(idx >> 6);
    const int c8 = ((int)idx & 63) * 8;
    unsigned short r[8];
#pragma unroll
    for (int j = 0; j < 8; ++j) {
      const int c = c8 + j;
      float v = 0.0f;
      if (node < N_NODES && c < F0) v = x[(size_t)node * F0 + c];
      r[j] = f2b(v);
    }
    *reinterpret_cast<uint4*>(xb + (size_t)node * KP + c8) = *reinterpret_cast<const uint4*>(r);
  }
}

// w [J,K] f32 -> wb [J,KP] bf16 (zero pad K)
__global__ __launch_bounds__(256) void convert_w_kernel(const float* __restrict__ w,
                                                        unsigned short* __restrict__ wb,
                                                        int J, int K) {
  const int total = J * KP;
  const int stride = gridDim.x * blockDim.x;
  for (int idx = blockIdx.x * blockDim.x + threadIdx.x; idx < total; idx += stride) {
    const int j = idx >> 9;           // KP = 512
    const int k = idx & (KP - 1);
    wb[idx] = (k < K) ? f2b(w[(size_t)j * K + k]) : (unsigned short)0;
  }
}

// ---------------- gather-mean (bf16 in/out, f32 accum), C=512, wave per node ----------------
__global__ __launch_bounds__(256) void gather_mean_bf512(
    const unsigned short* __restrict__ xb, const int* __restrict__ row_ptr,
    const int* __restrict__ csr_src, unsigned short* __restrict__ aggb)
{
  const int node = blockIdx.x * 4 + (threadIdx.x >> 6);
  const int t = threadIdx.x & 63;
  if (node >= M_PAD) return;
  if (node >= N_NODES) {                // zero pad rows (ws is not re-zeroed between replays)
    uintx4 z = (uintx4){0u, 0u, 0u, 0u};
    __builtin_nontemporal_store(z, (uintx4*)(aggb + (size_t)node * 512 + t * 8));
    return;
  }
  const int beg = row_ptr[node];
  const int end = row_ptr[node + 1];
  float acc[8] = {0.f, 0.f, 0.f, 0.f, 0.f, 0.f, 0.f, 0.f};
  int j = beg;
  for (; j + 3 < end; j += 4) {          // 4 outstanding 16B loads per lane
    const int s0 = csr_src[j];
    const int s1 = csr_src[j + 1];
    const int s2 = csr_src[j + 2];
    const int s3 = csr_src[j + 3];
    const uint4 v0 = *reinterpret_cast<const uint4*>(xb + (size_t)s0 * 512 + t * 8);
    const uint4 v1 = *reinterpret_cast<const uint4*>(xb + (size_t)s1 * 512 + t * 8);
    const uint4 v2 = *reinterpret_cast<const uint4*>(xb + (size_t)s2 * 512 + t * 8);
    const uint4 v3 = *reinterpret_cast<const uint4*>(xb + (size_t)s3 * 512 + t * 8);
    const unsigned int u0[4] = {v0.x, v0.y, v0.z, v0.w};
    const unsigned int u1[4] = {v1.x, v1.y, v1.z, v1.w};
    const unsigned int u2[4] = {v2.x, v2.y, v2.z, v2.w};
    const unsigned int u3[4] = {v3.x, v3.y, v3.z, v3.w};
#pragma unroll
    for (int q = 0; q < 4; ++q) {
      acc[2 * q]     += (b2f((unsigned short)(u0[q] & 0xFFFF)) + b2f((unsigned short)(u1[q] & 0xFFFF)))
                      + (b2f((unsigned short)(u2[q] & 0xFFFF)) + b2f((unsigned short)(u3[q] & 0xFFFF)));
      acc[2 * q + 1] += (b2f((unsigned short)(u0[q] >> 16)) + b2f((unsigned short)(u1[q] >> 16)))
                      + (b2f((unsigned short)(u2[q] >> 16)) + b2f((unsigned short)(u3[q] >> 16)));
    }
  }
  for (; j < end; ++j) {
    const int s0 = csr_src[j];
    const uint4 v0 = *reinterpret_cast<const uint4*>(xb + (size_t)s0 * 512 + t * 8);
    const unsigned int u0[4] = {v0.x, v0.y, v0.z, v0.w};
#pragma unroll
    for (int q = 0; q < 4; ++q) {
      acc[2 * q]     += b2f((unsigned short)(u0[q] & 0xFFFF));
      acc[2 * q + 1] += b2f((unsigned short)(u0[q] >> 16));
    }
  }
  const int deg = end - beg;
  const float inv = 1.0f / (float)(deg > 1 ? deg : 1);
  unsigned short r[8];
#pragma unroll
  for (int q = 0; q < 8; ++q) r[q] = f2b(acc[q] * inv);
  // nt store: agg is streamed once by the GEMM later; don't evict xb from L3
  __builtin_nontemporal_store(*reinterpret_cast<const uintx4*>(r),
                              (uintx4*)(aggb + (size_t)node * 512 + t * 8));
}

// ---------------- bf16 MFMA GEMM (optionally dual-A/B) ----------------
// T1 XCD chunk-swizzle over a COLUMN-MAJOR flatten: consecutive logical blocks on an
// XCD share the same A row-panel (128KB) -> A fetched ~once from HBM, re-reads hit L2.
// niter=16: C = A1@B1.T + A2@B2.T (K=512 each);  niter=8: C = A1@B1.T.
__global__ __launch_bounds__(256) void gemm_mfma(
    const unsigned short* __restrict__ A1, const unsigned short* __restrict__ A2,
    const unsigned short* __restrict__ B1, const unsigned short* __restrict__ B2,
    const float* __restrict__ bias, unsigned short* __restrict__ Cout,
    int J, int niter, int fuse, int relu)
{
  __shared__ __align__(16) unsigned short Alds[128 * 64];
  __shared__ __align__(16) unsigned short Blds[128 * 64];
  const int tid = threadIdx.x;
  const int lane = tid & 63;
  const int wid = tid >> 6;          // 4 waves

  // hw linear id (x fastest = hw dispatch order), chunked across 8 XCDs
  const int nwg = gridDim.x * gridDim.y;     // divisible by 8 for all our shapes
  int wg = blockIdx.y * gridDim.x + blockIdx.x;
  const int cpx = nwg >> 3;
  wg = (wg & 7) * cpx + (wg >> 3);
  // logical tile: COLUMN-major (row-panel fastest-varying dimension is by)
  const int brow = (wg / gridDim.y) * 128;
  const int bcol = (wg % gridDim.y) * 128;

  const int wr = wid >> 1;           // wave's 64x64 quadrant
  const int wc = wid & 1;

  f32x4 acc[4][4];
#pragma unroll
  for (int m = 0; m < 4; ++m)
#pragma unroll
    for (int n = 0; n < 4; ++n) acc[m][n] = (f32x4){0.f, 0.f, 0.f, 0.f};

  const int srow = lane >> 3;            // 0..7: row within 8-row stripe
  const int gchunk = (lane & 7) ^ srow;  // T2: pre-swizzled source 16B-chunk
  const int fr = lane & 15;              // fragment row/col
  const int fk = lane >> 4;              // fragment k-group (8 elems)

  for (int it = 0; it < niter; ++it) {
    const unsigned short* __restrict__ A = (it < 8) ? A1 : A2;
    const unsigned short* __restrict__ B = (it < 8) ? B1 : B2;
    const int k0 = (it & 7) * 64;
    __syncthreads();                 // previous tile's reads done before overwrite
#pragma unroll
    for (int i = 0; i < 4; ++i) {
      const int r = i * 32 + wid * 8;   // 8-row stripe per wave per iter
      __builtin_amdgcn_global_load_lds(
          (const __attribute__((address_space(1))) unsigned int*)(A + (size_t)(brow + r + srow) * KP + k0 + gchunk * 8),
          (__attribute__((address_space(3))) unsigned int*)(&Alds[r * 64]),
          16, 0, 0);
      __builtin_amdgcn_global_load_lds(
          (const __attribute__((address_space(1))) unsigned int*)(B + (size_t)(bcol + r + srow) * KP + k0 + gchunk * 8),
          (__attribute__((address_space(3))) unsigned int*)(&Blds[r * 64]),
          16, 0, 0);
    }
    __syncthreads();                 // staging visible (compiler drains vmcnt)
#pragma unroll
    for (int ks = 0; ks < 2; ++ks) {
      bf16x8 a[4], b[4];
#pragma unroll
      for (int m = 0; m < 4; ++m) {
        const int row = wr * 64 + m * 16 + fr;
        a[m] = *reinterpret_cast<const bf16x8*>(&Alds[row * 64 + (((ks * 4 + fk) ^ (fr & 7)) * 8)]);
      }
#pragma unroll
      for (int n = 0; n < 4; ++n) {
        const int row = wc * 64 + n * 16 + fr;
        b[n] = *reinterpret_cast<const bf16x8*>(&Blds[row * 64 + (((ks * 4 + fk) ^ (fr & 7)) * 8)]);
      }
#pragma unroll
      for (int m = 0; m < 4; ++m)
#pragma unroll
        for (int n = 0; n < 4; ++n)
          acc[m][n] = __builtin_amdgcn_mfma_f32_16x16x32_bf16(a[m], b[n], acc[m][n], 0, 0, 0);
    }
  }

  // epilogue: C/D layout col=lane&15, row=(lane>>4)*4+i  [m89-verified]
  const int crow0 = brow + wr * 64 + (lane >> 4) * 4;
  const int ccol0 = bcol + wc * 64 + (lane & 15);
#pragma unroll
  for (int n = 0; n < 4; ++n) {
    const int col = ccol0 + n * 16;
    const float bv = fuse ? bias[col] : 0.0f;
#pragma unroll
    for (int m = 0; m < 4; ++m) {
#pragma unroll
      for (int i = 0; i < 4; ++i) {
        const int row = crow0 + m * 16 + i;
        float v = acc[m][n][i] + bv;
        if (relu) v = fmaxf(v, 0.0f);
        Cout[(size_t)row * J + col] = f2b(v);
      }
    }
  }
}

// ---------------- combine layer 2: h2 = relu(mean-gather(y2[:, :256]) + y2[i, 256:] + b2) ----------------
__global__ __launch_bounds__(256) void combine2_kernel(
    const unsigned short* __restrict__ y, const int* __restrict__ row_ptr,
    const int* __restrict__ csr_src, const float* __restrict__ bias,
    unsigned short* __restrict__ h)
{
  const int node = blockIdx.x * 8 + (threadIdx.x >> 5);
  const int t = threadIdx.x & 31;        // 8 channels each -> 256
  if (node >= N_NODES) return;
  const int beg = row_ptr[node];
  const int end = row_ptr[node + 1];
  float acc[8] = {0.f, 0.f, 0.f, 0.f, 0.f, 0.f, 0.f, 0.f};
  int j = beg;
  for (; j + 3 < end; j += 4) {
    const int s0 = csr_src[j];
    const int s1 = csr_src[j + 1];
    const int s2 = csr_src[j + 2];
    const int s3 = csr_src[j + 3];
    const uint4 v0 = *reinterpret_cast<const uint4*>(y + (size_t)s0 * 512 + t * 8);
    const uint4 v1 = *reinterpret_cast<const uint4*>(y + (size_t)s1 * 512 + t * 8);
    const uint4 v2 = *reinterpret_cast<const uint4*>(y + (size_t)s2 * 512 + t * 8);
    const uint4 v3 = *reinterpret_cast<const uint4*>(y + (size_t)s3 * 512 + t * 8);
    const unsigned int u0[4] = {v0.x, v0.y, v0.z, v0.w};
    const unsigned int u1[4] = {v1.x, v1.y, v1.z, v1.w};
    const unsigned int u2[4] = {v2.x, v2.y, v2.z, v2.w};
    const unsigned int u3[4] = {v3.x, v3.y, v3.z, v3.w};
#pragma unroll
    for (int q = 0; q < 4; ++q) {
      acc[2 * q]     += (b2f((unsigned short)(u0[q] & 0xFFFF)) + b2f((unsigned short)(u1[q] & 0xFFFF)))
                      + (b2f((unsigned short)(u2[q] & 0xFFFF)) + b2f((unsigned short)(u3[q] & 0xFFFF)));
      acc[2 * q + 1] += (b2f((unsigned short)(u0[q] >> 16)) + b2f((unsigned short)(u1[q] >> 16)))
                      + (b2f((unsigned short)(u2[q] >> 16)) + b2f((unsigned short)(u3[q] >> 16)));
    }
  }
  for (; j < end; ++j) {
    const int s0 = csr_src[j];
    const uint4 v0 = *reinterpret_cast<const uint4*>(y + (size_t)s0 * 512 + t * 8);
    const unsigned int u0[4] = {v0.x, v0.y, v0.z, v0.w};
#pragma unroll
    for (int q = 0; q < 4; ++q) {
      acc[2 * q]     += b2f((unsigned short)(u0[q] & 0xFFFF));
      acc[2 * q + 1] += b2f((unsigned short)(u0[q] >> 16));
    }
  }
  const int deg = end - beg;
  const float inv = 1.0f / (float)(deg > 1 ? deg : 1);
  const uint4 rv = *reinterpret_cast<const uint4*>(y + (size_t)node * 512 + 256 + t * 8);
  const unsigned int ru[4] = {rv.x, rv.y, rv.z, rv.w};
  unsigned short r[8];
#pragma unroll
  for (int q = 0; q < 4; ++q) {
    const float y0 = b2f((unsigned short)(ru[q] & 0xFFFF));
    const float y1 = b2f((unsigned short)(ru[q] >> 16));
    const float c0 = acc[2 * q] * inv + y0 + bias[t * 8 + 2 * q];
    const float c1 = acc[2 * q + 1] * inv + y1 + bias[t * 8 + 2 * q + 1];
    r[2 * q]     = f2b(fmaxf(c0, 0.0f));
    r[2 * q + 1] = f2b(fmaxf(c1, 0.0f));
  }
  *reinterpret_cast<uint4*>(h + (size_t)node * 256 + t * 8) = *reinterpret_cast<const uint4*>(r);
}

// ---------------- layer 3 projection: y3[n, 0..6] = h2[n]@wl3.T, y3[n, 8..14] = h2[n]@wr3.T ----------------
__global__ __launch_bounds__(256) void gemm3_node(
    const unsigned short* __restrict__ h2, const float* __restrict__ wl,
    const float* __restrict__ wr, unsigned short* __restrict__ y3, int N)
{
  const int node = (blockIdx.x * 256 + threadIdx.x) >> 6;
  const int lane = threadIdx.x & 63;
  if (node >= N) return;
  const uint2 hu = *reinterpret_cast<const uint2*>(h2 + (size_t)node * F2 + lane * 4);
  const float h0 = b2f((unsigned short)(hu.x & 0xFFFF)), h1 = b2f((unsigned short)(hu.x >> 16));
  const float h2v = b2f((unsigned short)(hu.y & 0xFFFF)), h3 = b2f((unsigned short)(hu.y >> 16));
#pragma unroll
  for (int j = 0; j < F3; ++j) {
    const float4 l4 = *reinterpret_cast<const float4*>(wl + j * F2 + lane * 4);
    const float4 r4 = *reinterpret_cast<const float4*>(wr + j * F2 + lane * 4);
    float tl = h0 * l4.x + h1 * l4.y + h2v * l4.z + h3 * l4.w;
    float tr = h0 * r4.x + h1 * r4.y + h2v * r4.z + h3 * r4.w;
#pragma unroll
    for (int m = 1; m < 64; m <<= 1) {
      tl += __shfl_xor(tl, m, 64);
      tr += __shfl_xor(tr, m, 64);
    }
    if (lane == 0) {
      y3[(size_t)node * 16 + j]     = f2b(tl);
      y3[(size_t)node * 16 + 8 + j] = f2b(tr);
    }
  }
}

// ---------------- combine layer 3: out = mean-gather(y3[:, 0..6]) + y3[i, 8..14] + b3 ----------------
__global__ __launch_bounds__(256) void combine3_kernel(
    const unsigned short* __restrict__ y3, const int* __restrict__ row_ptr,
    const int* __restrict__ csr_src, const float* __restrict__ b3,
    float* __restrict__ out, int N)
{
  const int node = blockIdx.x * 256 + threadIdx.x;
  if (node >= N) return;
  const int beg = row_ptr[node];
  const int end = row_ptr[node + 1];
  float acc[8] = {0.f, 0.f, 0.f, 0.f, 0.f, 0.f, 0.f, 0.f};
  for (int j = beg; j < end; ++j) {
    const int s = csr_src[j];
    const uint4 v = *reinterpret_cast<const uint4*>(y3 + (size_t)s * 16);
    const unsigned int u[4] = {v.x, v.y, v.z, v.w};
#pragma unroll
    for (int q = 0; q < 4; ++q) {
      acc[2 * q]     += b2f((unsigned short)(u[q] & 0xFFFF));
      acc[2 * q + 1] += b2f((unsigned short)(u[q] >> 16));
    }
  }
  const int deg = end - beg;
  const float inv = 1.0f / (float)(deg > 1 ? deg : 1);
  const uint4 rv = *reinterpret_cast<const uint4*>(y3 + (size_t)node * 16 + 8);
  const unsigned int ru[4] = {rv.x, rv.y, rv.z, rv.w};
  float yr[8];
#pragma unroll
  for (int q = 0; q < 4; ++q) {
    yr[2 * q]     = b2f((unsigned short)(ru[q] & 0xFFFF));
    yr[2 * q + 1] = b2f((unsigned short)(ru[q] >> 16));
  }
#pragma unroll
  for (int q = 0; q < F3; ++q)
    out[(size_t)node * F3 + q] = acc[q] * inv + yr[q] + b3[q];
}

extern "C" void kernel_launch(void* const* d_in, const int* in_sizes, int n_in,
                              void* d_out, int out_size, void* d_ws, size_t ws_size,
                              hipStream_t stream) {
  const float* x    = (const float*)d_in[0];
  const int*   ei   = (const int*)d_in[1];
  const float* w_l1 = (const float*)d_in[2];
  const float* w_r1 = (const float*)d_in[3];
  const float* b1   = (const float*)d_in[4];
  const float* w_l2 = (const float*)d_in[5];
  const float* w_r2 = (const float*)d_in[6];
  const float* b2   = (const float*)d_in[7];
  const float* w_l3 = (const float*)d_in[8];
  const float* w_r3 = (const float*)d_in[9];
  const float* b3   = (const float*)d_in[10];
  float* out = (float*)d_out;

  const int E = in_sizes[1] / 2;
  const int* src = ei;
  const int* dst = ei + E;

  // ---- workspace carve-up
  char* p = (char*)d_ws;
  int* row_ptr = (int*)p;           p += (size_t)(N_NODES + 1) * 4;
  int* cnt     = (int*)p;           p += (size_t)N_NODES * 4;
  int* bsum    = (int*)p;           p += 1024 * 4;
  int* csr_src = (int*)p;           p += (size_t)E * 4;
  p = (char*)(((uintptr_t)p + 255) & ~(uintptr_t)255);
  unsigned short* xb   = (unsigned short*)p;  p += (size_t)M_PAD * KP * 2;  // also reused as y2
  unsigned short* aggb = (unsigned short*)p;  p += (size_t)M_PAD * KP * 2;  // also reused as h2
  unsigned short* h1b  = (unsigned short*)p;  p += (size_t)M_PAD * KP * 2;  // also reused as y3
  unsigned short* wl1b = (unsigned short*)p;  p += (size_t)F1 * KP * 2;
  unsigned short* wr1b = (unsigned short*)p;  p += (size_t)F1 * KP * 2;
  unsigned short* w2b  = (unsigned short*)p;  p += (size_t)F1 * KP * 2;     // concat [wl2; wr2] -> 512 rows

  unsigned short* y2  = xb;     // [M_PAD, 512] (cols 0..255 = yl2, 256..511 = yr2); xb dead after GEMM1
  unsigned short* h2b = aggb;   // [M_PAD, 256]; aggb dead after GEMM1
  unsigned short* y3  = h1b;    // [M_PAD, 16];  h1b dead after GEMM2

  const int nb = cdiv_i(N_NODES, 1024);   // 88

  // ---- CSR build
  hipMemsetAsync(cnt, 0, (size_t)N_NODES * sizeof(int), stream);
  degree_kernel<<<cdiv_i(E, 256), 256, 0, stream>>>(dst, cnt, E);
  scan_partial<<<nb, 1024, 0, stream>>>(cnt, row_ptr, bsum, N_NODES);
  scan_bsums<<<1, 1024, 0, stream>>>(bsum, nb);
  scan_add<<<nb, 1024, 0, stream>>>(row_ptr, bsum, cnt, N_NODES, E);   // cnt becomes cursor
  fill_kernel<<<cdiv_i(E, 256), 256, 0, stream>>>(src, dst, cnt, csr_src, E);

  // ---- conversions
  convert_x_kernel<<<2048, 256, 0, stream>>>(x, xb);
  convert_w_kernel<<<512, 256, 0, stream>>>(w_l1, wl1b, F1, F0);
  convert_w_kernel<<<512, 256, 0, stream>>>(w_r1, wr1b, F1, F0);
  convert_w_kernel<<<256, 256, 0, stream>>>(w_l2, w2b, F2, F1);                   // rows 0..255
  convert_w_kernel<<<256, 256, 0, stream>>>(w_r2, w2b + (size_t)F2 * KP, F2, F1); // rows 256..511

  // ---- layer 1: agg = mean-gather(x);  h1 = relu(agg@wl1.T + x@wr1.T + b1)
  gather_mean_bf512<<<cdiv_i(M_PAD, 4), 256, 0, stream>>>(xb, row_ptr, csr_src, aggb);
  {
    dim3 g(M_PAD / 128, F1 / 128);
    gemm_mfma<<<g, 256, 0, stream>>>(aggb, xb, wl1b, wr1b, b1, h1b, F1, 16, 1, 1);
  }

  // ---- layer 2 (aggregate AFTER projection): y2 = h1 @ [wl2; wr2].T, then combine
  {
    dim3 g(M_PAD / 128, 512 / 128);
    gemm_mfma<<<g, 256, 0, stream>>>(h1b, h1b, w2b, w2b, (const float*)nullptr, y2, 512, 8, 0, 0);
  }
  combine2_kernel<<<cdiv_i(N_NODES, 8), 256, 0, stream>>>(y2, row_ptr, csr_src, b2, h2b);

  // ---- layer 3: project to 7+7, then combine
  gemm3_node<<<cdiv_i(N_NODES * 64, 256), 256, 0, stream>>>(h2b, w_l3, w_r3, y3, N_NODES);
  combine3_kernel<<<cdiv_i(N_NODES, 256), 256, 0, stream>>>(y3, row_ptr, csr_src, b3, out, N_NODES);
}

// Round 6
// 634.033 us; speedup vs baseline: 28.0887x; 1.0826x over previous
//
#include <hip/hip_runtime.h>
#include <cstdint>
#include <cstddef>

#define N_NODES 89250
#define M_PAD   89344   // 698 * 128
#define F0 500
#define F1 512
#define F2 256
#define F3 7
#define KP 512          // padded K for the MFMA GEMMs

typedef __attribute__((ext_vector_type(8))) short bf16x8;   // 8 bf16 = 4 VGPRs
typedef __attribute__((ext_vector_type(4))) float f32x4;

static inline int cdiv_i(int a, int b) { return (a + b - 1) / b; }

__device__ __forceinline__ unsigned short f2b(float f) {
  unsigned int u = __float_as_uint(f);
  u = (u + 0x7FFFu + ((u >> 16) & 1u)) >> 16;
  return (unsigned short)u;
}
__device__ __forceinline__ float b2f(unsigned short h) {
  return __uint_as_float(((unsigned int)h) << 16);
}

// ---------------- CSR build ----------------
__global__ void degree_kernel(const int* __restrict__ dst, int* __restrict__ cnt, int E) {
  int stride = gridDim.x * blockDim.x;
  for (int i = blockIdx.x * blockDim.x + threadIdx.x; i < E; i += stride)
    atomicAdd(&cnt[dst[i]], 1);
}

__global__ __launch_bounds__(1024) void scan_partial(const int* __restrict__ cnt,
                                                     int* __restrict__ row_ptr,
                                                     int* __restrict__ bsum, int n) {
  __shared__ int sm[1024];
  const int i = blockIdx.x * 1024 + threadIdx.x;
  const int v = (i < n) ? cnt[i] : 0;
  sm[threadIdx.x] = v;
  __syncthreads();
  for (int off = 1; off < 1024; off <<= 1) {
    int t = (threadIdx.x >= off) ? sm[threadIdx.x - off] : 0;
    __syncthreads();
    sm[threadIdx.x] += t;
    __syncthreads();
  }
  if (i < n) row_ptr[i] = sm[threadIdx.x] - v;    // block-local exclusive
  if (threadIdx.x == 1023) bsum[blockIdx.x] = sm[1023];
}

__global__ __launch_bounds__(1024) void scan_bsums(int* __restrict__ bsum, int nb) {
  __shared__ int sm[1024];
  const int v = (threadIdx.x < nb) ? bsum[threadIdx.x] : 0;
  sm[threadIdx.x] = v;
  __syncthreads();
  for (int off = 1; off < 1024; off <<= 1) {
    int t = (threadIdx.x >= off) ? sm[threadIdx.x - off] : 0;
    __syncthreads();
    sm[threadIdx.x] += t;
    __syncthreads();
  }
  if (threadIdx.x < nb) bsum[threadIdx.x] = sm[threadIdx.x] - v;  // exclusive
}

// adds block offsets AND initializes cursor = row_ptr (saves a pass)
__global__ __launch_bounds__(1024) void scan_add(int* __restrict__ row_ptr,
                                                 const int* __restrict__ bsum,
                                                 int* __restrict__ cursor,
                                                 int n, int total) {
  const int i = blockIdx.x * 1024 + threadIdx.x;
  if (i < n) {
    const int v = row_ptr[i] + bsum[i >> 10];
    row_ptr[i] = v;
    cursor[i] = v;
  }
  if (i == 0) row_ptr[n] = total;
}

__global__ void fill_kernel(const int* __restrict__ src, const int* __restrict__ dst,
                            int* __restrict__ cursor, int* __restrict__ csr_src, int E) {
  int stride = gridDim.x * blockDim.x;
  for (int i = blockIdx.x * blockDim.x + threadIdx.x; i < E; i += stride) {
    const int p = atomicAdd(&cursor[dst[i]], 1);
    csr_src[p] = src[i];
  }
}

// ---------------- conversions to bf16 ----------------
__global__ __launch_bounds__(256) void convert_x_kernel(const float* __restrict__ x,
                                                        unsigned short* __restrict__ xb) {
  const long long total = (long long)M_PAD * (KP / 8);
  const long long stride = (long long)gridDim.x * blockDim.x;
  for (long long idx = (long long)blockIdx.x * blockDim.x + threadIdx.x; idx < total; idx += stride) {
    const int node = (int)(idx >> 6);
    const int c8 = ((int)idx & 63) * 8;
    unsigned short r[8];
#pragma unroll
    for (int j = 0; j < 8; ++j) {
      const int c = c8 + j;
      float v = 0.0f;
      if (node < N_NODES && c < F0) v = x[(size_t)node * F0 + c];
      r[j] = f2b(v);
    }
    *reinterpret_cast<uint4*>(xb + (size_t)node * KP + c8) = *reinterpret_cast<const uint4*>(r);
  }
}

// all weights in one kernel: wl1/wr1 [512,500]->[512,512]; wl2/wr2 [256,512]->w2b concat;
// wl3/wr3 [7,256] -> w3b [16,256] (rows 0..6 = wl3, 8..14 = wr3, 7/15 zero)
__global__ __launch_bounds__(256) void convert_w_all(
    const float* __restrict__ wl1, const float* __restrict__ wr1,
    const float* __restrict__ wl2, const float* __restrict__ wr2,
    const float* __restrict__ wl3, const float* __restrict__ wr3,
    unsigned short* __restrict__ wl1b, unsigned short* __restrict__ wr1b,
    unsigned short* __restrict__ w2b, unsigned short* __restrict__ w3b)
{
  int idx = blockIdx.x * 256 + threadIdx.x;
  const int S1 = F1 * KP;          // 262144, covers wl1 AND wr1
  if (idx < S1) {
    const int j = idx >> 9, k = idx & 511;
    const bool in = (k < F0);
    wl1b[idx] = in ? f2b(wl1[(size_t)j * F0 + k]) : (unsigned short)0;
    wr1b[idx] = in ? f2b(wr1[(size_t)j * F0 + k]) : (unsigned short)0;
    return;
  }
  idx -= S1;
  const int S2 = F2 * KP;          // 131072, covers wl2 AND wr2 (K=512 exact)
  if (idx < S2) {
    w2b[idx] = f2b(wl2[idx]);
    w2b[S2 + idx] = f2b(wr2[idx]);
    return;
  }
  idx -= S2;
  if (idx < 16 * 256) {
    const int j = idx >> 8, k = idx & 255;
    float v = 0.0f;
    if (j < 7) v = wl3[(size_t)j * F2 + k];
    else if (j >= 8 && j < 15) v = wr3[(size_t)(j - 8) * F2 + k];
    w3b[idx] = f2b(v);
  }
}

// ---------------- gather-mean (bf16 in/out, f32 accum), C=512, wave per node ----------------
// masked 8-deep batches: uniform MLP of 8 outstanding 16B loads, no serial tail
__global__ __launch_bounds__(256) void gather_mean_bf512(
    const unsigned short* __restrict__ xb, const int* __restrict__ row_ptr,
    const int* __restrict__ csr_src, unsigned short* __restrict__ aggb)
{
  const int node = blockIdx.x * 4 + (threadIdx.x >> 6);
  const int t = threadIdx.x & 63;
  if (node >= M_PAD) return;
  if (node >= N_NODES) {                // zero pad rows (ws is not re-zeroed between replays)
    *reinterpret_cast<uint4*>(aggb + (size_t)node * 512 + t * 8) = make_uint4(0, 0, 0, 0);
    return;
  }
  const int beg = row_ptr[node];
  const int end = row_ptr[node + 1];
  float acc[8] = {0.f, 0.f, 0.f, 0.f, 0.f, 0.f, 0.f, 0.f};
  for (int j = beg; j < end; j += 8) {
    uint4 v[8];
    float m[8];
#pragma unroll
    for (int u = 0; u < 8; ++u) {
      const int e = min(j + u, end - 1);
      m[u] = (j + u < end) ? 1.0f : 0.0f;
      v[u] = *reinterpret_cast<const uint4*>(xb + (size_t)csr_src[e] * 512 + t * 8);
    }
#pragma unroll
    for (int u = 0; u < 8; ++u) {
      const unsigned int w[4] = {v[u].x, v[u].y, v[u].z, v[u].w};
#pragma unroll
      for (int q = 0; q < 4; ++q) {
        acc[2 * q]     = fmaf(m[u], b2f((unsigned short)(w[q] & 0xFFFF)), acc[2 * q]);
        acc[2 * q + 1] = fmaf(m[u], b2f((unsigned short)(w[q] >> 16)),    acc[2 * q + 1]);
      }
    }
  }
  const int deg = end - beg;
  const float inv = 1.0f / (float)(deg > 1 ? deg : 1);
  unsigned short r[8];
#pragma unroll
  for (int q = 0; q < 8; ++q) r[q] = f2b(acc[q] * inv);
  *reinterpret_cast<uint4*>(aggb + (size_t)node * 512 + t * 8) = *reinterpret_cast<const uint4*>(r);
}

// ---------------- bf16 MFMA GEMM (optionally dual-A/B) ----------------
// T1 XCD chunk-swizzle over a COLUMN-MAJOR flatten + T2 LDS swizzle (rule-21-correct).
// niter=16: C = A1@B1.T + A2@B2.T (K=512 each);  niter=8: C = A1@B1.T.
__global__ __launch_bounds__(256) void gemm_mfma(
    const unsigned short* __restrict__ A1, const unsigned short* __restrict__ A2,
    const unsigned short* __restrict__ B1, const unsigned short* __restrict__ B2,
    const float* __restrict__ bias, unsigned short* __restrict__ Cout,
    int J, int niter, int fuse, int relu)
{
  __shared__ __align__(16) unsigned short Alds[128 * 64];
  __shared__ __align__(16) unsigned short Blds[128 * 64];
  const int tid = threadIdx.x;
  const int lane = tid & 63;
  const int wid = tid >> 6;          // 4 waves

  const int nwg = gridDim.x * gridDim.y;     // divisible by 8 for all our shapes
  int wg = blockIdx.y * gridDim.x + blockIdx.x;
  const int cpx = nwg >> 3;
  wg = (wg & 7) * cpx + (wg >> 3);
  const int brow = (wg / gridDim.y) * 128;
  const int bcol = (wg % gridDim.y) * 128;

  const int wr = wid >> 1;           // wave's 64x64 quadrant
  const int wc = wid & 1;

  f32x4 acc[4][4];
#pragma unroll
  for (int m = 0; m < 4; ++m)
#pragma unroll
    for (int n = 0; n < 4; ++n) acc[m][n] = (f32x4){0.f, 0.f, 0.f, 0.f};

  const int srow = lane >> 3;            // 0..7: row within 8-row stripe
  const int gchunk = (lane & 7) ^ srow;  // T2: pre-swizzled source 16B-chunk
  const int fr = lane & 15;              // fragment row/col
  const int fk = lane >> 4;              // fragment k-group (8 elems)

  for (int it = 0; it < niter; ++it) {
    const unsigned short* __restrict__ A = (it < 8) ? A1 : A2;
    const unsigned short* __restrict__ B = (it < 8) ? B1 : B2;
    const int k0 = (it & 7) * 64;
    __syncthreads();                 // previous tile's reads done before overwrite
#pragma unroll
    for (int i = 0; i < 4; ++i) {
      const int r = i * 32 + wid * 8;   // 8-row stripe per wave per iter
      __builtin_amdgcn_global_load_lds(
          (const __attribute__((address_space(1))) unsigned int*)(A + (size_t)(brow + r + srow) * KP + k0 + gchunk * 8),
          (__attribute__((address_space(3))) unsigned int*)(&Alds[r * 64]),
          16, 0, 0);
      __builtin_amdgcn_global_load_lds(
          (const __attribute__((address_space(1))) unsigned int*)(B + (size_t)(bcol + r + srow) * KP + k0 + gchunk * 8),
          (__attribute__((address_space(3))) unsigned int*)(&Blds[r * 64]),
          16, 0, 0);
    }
    __syncthreads();                 // staging visible (compiler drains vmcnt)
#pragma unroll
    for (int ks = 0; ks < 2; ++ks) {
      bf16x8 a[4], b[4];
#pragma unroll
      for (int m = 0; m < 4; ++m) {
        const int row = wr * 64 + m * 16 + fr;
        a[m] = *reinterpret_cast<const bf16x8*>(&Alds[row * 64 + (((ks * 4 + fk) ^ (fr & 7)) * 8)]);
      }
#pragma unroll
      for (int n = 0; n < 4; ++n) {
        const int row = wc * 64 + n * 16 + fr;
        b[n] = *reinterpret_cast<const bf16x8*>(&Blds[row * 64 + (((ks * 4 + fk) ^ (fr & 7)) * 8)]);
      }
#pragma unroll
      for (int m = 0; m < 4; ++m)
#pragma unroll
        for (int n = 0; n < 4; ++n)
          acc[m][n] = __builtin_amdgcn_mfma_f32_16x16x32_bf16(a[m], b[n], acc[m][n], 0, 0, 0);
    }
  }

  // epilogue: C/D layout col=lane&15, row=(lane>>4)*4+i  [m89-verified]
  const int crow0 = brow + wr * 64 + (lane >> 4) * 4;
  const int ccol0 = bcol + wc * 64 + (lane & 15);
#pragma unroll
  for (int n = 0; n < 4; ++n) {
    const int col = ccol0 + n * 16;
    const float bv = fuse ? bias[col] : 0.0f;
#pragma unroll
    for (int m = 0; m < 4; ++m) {
#pragma unroll
      for (int i = 0; i < 4; ++i) {
        const int row = crow0 + m * 16 + i;
        float v = acc[m][n][i] + bv;
        if (relu) v = fmaxf(v, 0.0f);
        Cout[(size_t)row * J + col] = f2b(v);
      }
    }
  }
}

// ---------------- combine layer 2: h2 = relu(mean-gather(y2[:, :256]) + y2[i, 256:] + b2) ----------------
__global__ __launch_bounds__(256) void combine2_kernel(
    const unsigned short* __restrict__ y, const int* __restrict__ row_ptr,
    const int* __restrict__ csr_src, const float* __restrict__ bias,
    unsigned short* __restrict__ h)
{
  const int node = blockIdx.x * 8 + (threadIdx.x >> 5);
  const int t = threadIdx.x & 31;        // 8 channels each -> 256
  if (node >= N_NODES) return;
  const int beg = row_ptr[node];
  const int end = row_ptr[node + 1];
  float acc[8] = {0.f, 0.f, 0.f, 0.f, 0.f, 0.f, 0.f, 0.f};
  for (int j = beg; j < end; j += 8) {
    uint4 v[8];
    float m[8];
#pragma unroll
    for (int u = 0; u < 8; ++u) {
      const int e = min(j + u, end - 1);
      m[u] = (j + u < end) ? 1.0f : 0.0f;
      v[u] = *reinterpret_cast<const uint4*>(y + (size_t)csr_src[e] * 512 + t * 8);
    }
#pragma unroll
    for (int u = 0; u < 8; ++u) {
      const unsigned int w[4] = {v[u].x, v[u].y, v[u].z, v[u].w};
#pragma unroll
      for (int q = 0; q < 4; ++q) {
        acc[2 * q]     = fmaf(m[u], b2f((unsigned short)(w[q] & 0xFFFF)), acc[2 * q]);
        acc[2 * q + 1] = fmaf(m[u], b2f((unsigned short)(w[q] >> 16)),    acc[2 * q + 1]);
      }
    }
  }
  const int deg = end - beg;
  const float inv = 1.0f / (float)(deg > 1 ? deg : 1);
  const uint4 rv = *reinterpret_cast<const uint4*>(y + (size_t)node * 512 + 256 + t * 8);
  const unsigned int ru[4] = {rv.x, rv.y, rv.z, rv.w};
  unsigned short r[8];
#pragma unroll
  for (int q = 0; q < 4; ++q) {
    const float y0 = b2f((unsigned short)(ru[q] & 0xFFFF));
    const float y1 = b2f((unsigned short)(ru[q] >> 16));
    const float c0 = acc[2 * q] * inv + y0 + bias[t * 8 + 2 * q];
    const float c1 = acc[2 * q + 1] * inv + y1 + bias[t * 8 + 2 * q + 1];
    r[2 * q]     = f2b(fmaxf(c0, 0.0f));
    r[2 * q + 1] = f2b(fmaxf(c1, 0.0f));
  }
  *reinterpret_cast<uint4*>(h + (size_t)node * 256 + t * 8) = *reinterpret_cast<const uint4*>(r);
}

// ---------------- layer 3 projection via MFMA: y3[M,16] = h2 @ w3b.T ----------------
// w3b [16,256]: rows 0..6 = wl3, 8..14 = wr3. One wave -> 16 node-rows, K=256 = 8 mfma.
__global__ __launch_bounds__(256) void gemm3_mfma(
    const unsigned short* __restrict__ h2b, const unsigned short* __restrict__ w3b,
    unsigned short* __restrict__ y3)
{
  const int wave = threadIdx.x >> 6, lane = threadIdx.x & 63;
  const int rowbase = blockIdx.x * 64 + wave * 16;
  const int fr = lane & 15, fk = lane >> 4;
  bf16x8 b[8];
#pragma unroll
  for (int ks = 0; ks < 8; ++ks)
    b[ks] = *reinterpret_cast<const bf16x8*>(w3b + fr * 256 + ks * 32 + fk * 8);
  f32x4 acc = (f32x4){0.f, 0.f, 0.f, 0.f};
#pragma unroll
  for (int ks = 0; ks < 8; ++ks) {
    const bf16x8 a = *reinterpret_cast<const bf16x8*>(h2b + (size_t)(rowbase + fr) * 256 + ks * 32 + fk * 8);
    acc = __builtin_amdgcn_mfma_f32_16x16x32_bf16(a, b[ks], acc, 0, 0, 0);
  }
  const int r0 = rowbase + fk * 4;
#pragma unroll
  for (int i = 0; i < 4; ++i)
    y3[(size_t)(r0 + i) * 16 + fr] = f2b(acc[i]);
}

// ---------------- combine layer 3: out = mean-gather(y3[:, 0..6]) + y3[i, 8..14] + b3 ----------------
// wave per node: lanes take edges in parallel, shfl-xor reduce
__global__ __launch_bounds__(256) void combine3_kernel(
    const unsigned short* __restrict__ y3, const int* __restrict__ row_ptr,
    const int* __restrict__ csr_src, const float* __restrict__ b3,
    float* __restrict__ out, int N)
{
  const int node = blockIdx.x * 4 + (threadIdx.x >> 6);
  const int lane = threadIdx.x & 63;
  if (node >= N) return;
  const int beg = row_ptr[node];
  const int end = row_ptr[node + 1];
  float acc[7] = {0.f, 0.f, 0.f, 0.f, 0.f, 0.f, 0.f};
  for (int j = beg + lane; j < end; j += 64) {
    const int s = csr_src[j];
    const uint4 v = *reinterpret_cast<const uint4*>(y3 + (size_t)s * 16);
    const unsigned int u[4] = {v.x, v.y, v.z, v.w};
#pragma unroll
    for (int q = 0; q < 7; ++q) {
      const unsigned short hw = (unsigned short)((u[q >> 1] >> ((q & 1) * 16)) & 0xFFFF);
      acc[q] += b2f(hw);
    }
  }
#pragma unroll
  for (int q = 0; q < 7; ++q)
#pragma unroll
    for (int m = 1; m < 64; m <<= 1)
      acc[q] += __shfl_xor(acc[q], m, 64);
  if (lane == 0) {
    const int deg = end - beg;
    const float inv = 1.0f / (float)(deg > 1 ? deg : 1);
    const uint4 rv = *reinterpret_cast<const uint4*>(y3 + (size_t)node * 16 + 8);
    const unsigned int ru[4] = {rv.x, rv.y, rv.z, rv.w};
#pragma unroll
    for (int q = 0; q < 7; ++q) {
      const float self = b2f((unsigned short)((ru[q >> 1] >> ((q & 1) * 16)) & 0xFFFF));
      out[(size_t)node * F3 + q] = acc[q] * inv + self + b3[q];
    }
  }
}

extern "C" void kernel_launch(void* const* d_in, const int* in_sizes, int n_in,
                              void* d_out, int out_size, void* d_ws, size_t ws_size,
                              hipStream_t stream) {
  const float* x    = (const float*)d_in[0];
  const int*   ei   = (const int*)d_in[1];
  const float* w_l1 = (const float*)d_in[2];
  const float* w_r1 = (const float*)d_in[3];
  const float* b1   = (const float*)d_in[4];
  const float* w_l2 = (const float*)d_in[5];
  const float* w_r2 = (const float*)d_in[6];
  const float* b2   = (const float*)d_in[7];
  const float* w_l3 = (const float*)d_in[8];
  const float* w_r3 = (const float*)d_in[9];
  const float* b3   = (const float*)d_in[10];
  float* out = (float*)d_out;

  const int E = in_sizes[1] / 2;
  const int* src = ei;
  const int* dst = ei + E;

  // ---- workspace carve-up
  char* p = (char*)d_ws;
  int* row_ptr = (int*)p;           p += (size_t)(N_NODES + 1) * 4;
  int* cnt     = (int*)p;           p += (size_t)N_NODES * 4;
  int* bsum    = (int*)p;           p += 1024 * 4;
  int* csr_src = (int*)p;           p += (size_t)E * 4;
  p = (char*)(((uintptr_t)p + 255) & ~(uintptr_t)255);
  unsigned short* xb   = (unsigned short*)p;  p += (size_t)M_PAD * KP * 2;  // also reused as y2
  unsigned short* aggb = (unsigned short*)p;  p += (size_t)M_PAD * KP * 2;  // also reused as h2
  unsigned short* h1b  = (unsigned short*)p;  p += (size_t)M_PAD * KP * 2;  // also reused as y3
  unsigned short* wl1b = (unsigned short*)p;  p += (size_t)F1 * KP * 2;
  unsigned short* wr1b = (unsigned short*)p;  p += (size_t)F1 * KP * 2;
  unsigned short* w2b  = (unsigned short*)p;  p += (size_t)F1 * KP * 2;     // concat [wl2; wr2] -> 512 rows
  unsigned short* w3b  = (unsigned short*)p;  p += (size_t)16 * F2 * 2;     // [16,256]

  unsigned short* y2  = xb;     // [M_PAD, 512]; xb dead after GEMM1
  unsigned short* h2b = aggb;   // [M_PAD, 256]; aggb dead after GEMM1
  unsigned short* y3  = h1b;    // [M_PAD, 16];  h1b dead after GEMM2

  const int nb = cdiv_i(N_NODES, 1024);   // 88

  // ---- CSR build
  hipMemsetAsync(cnt, 0, (size_t)N_NODES * sizeof(int), stream);
  degree_kernel<<<cdiv_i(E, 256), 256, 0, stream>>>(dst, cnt, E);
  scan_partial<<<nb, 1024, 0, stream>>>(cnt, row_ptr, bsum, N_NODES);
  scan_bsums<<<1, 1024, 0, stream>>>(bsum, nb);
  scan_add<<<nb, 1024, 0, stream>>>(row_ptr, bsum, cnt, N_NODES, E);   // cnt becomes cursor
  fill_kernel<<<cdiv_i(E, 256), 256, 0, stream>>>(src, dst, cnt, csr_src, E);

  // ---- conversions
  convert_x_kernel<<<2048, 256, 0, stream>>>(x, xb);
  {
    const int total = F1 * KP + F2 * KP + 16 * F2;
    convert_w_all<<<cdiv_i(total, 256), 256, 0, stream>>>(
        w_l1, w_r1, w_l2, w_r2, w_l3, w_r3, wl1b, wr1b, w2b, w3b);
  }

  // ---- layer 1: agg = mean-gather(x);  h1 = relu(agg@wl1.T + x@wr1.T + b1)
  gather_mean_bf512<<<cdiv_i(M_PAD, 4), 256, 0, stream>>>(xb, row_ptr, csr_src, aggb);
  {
    dim3 g(M_PAD / 128, F1 / 128);
    gemm_mfma<<<g, 256, 0, stream>>>(aggb, xb, wl1b, wr1b, b1, h1b, F1, 16, 1, 1);
  }

  // ---- layer 2 (aggregate AFTER projection): y2 = h1 @ [wl2; wr2].T, then combine
  {
    dim3 g(M_PAD / 128, 512 / 128);
    gemm_mfma<<<g, 256, 0, stream>>>(h1b, h1b, w2b, w2b, (const float*)nullptr, y2, 512, 8, 0, 0);
  }
  combine2_kernel<<<cdiv_i(N_NODES, 8), 256, 0, stream>>>(y2, row_ptr, csr_src, b2, h2b);

  // ---- layer 3: MFMA projection to [M,16], then combine
  gemm3_mfma<<<M_PAD / 64, 256, 0, stream>>>(h2b, w3b, y3);
  combine3_kernel<<<cdiv_i(N_NODES, 4), 256, 0, stream>>>(y3, row_ptr, csr_src, b3, out, N_NODES);
}